// Round 10
// baseline (754.956 us; speedup 1.0000x reference)
//
#include <hip/hip_runtime.h>
#include <hip/hip_fp16.h>
#include <cstdint>
#include <cstddef>
#include <cstring>

#define DIM 128
#define NEG_SLOPE 0.2f

#define CHUNK_E_LOG 13            // 8192-item chunks for edge ranking
#define CHUNK_N_LOG 15            // 32768-item chunks for node ranking
#define SUBBINS 16384             // 64 KB LDS histogram subrange

typedef _Float16 half8v __attribute__((ext_vector_type(8)));
typedef __attribute__((ext_vector_type(4))) float float4v;

// ---- fp16 helpers ----------------------------------------------------------
__device__ __forceinline__ float2 h2f2(uint u) {
  __half2 h;
  __builtin_memcpy(&h, &u, 4);
  return __half22float2(h);
}
__device__ __forceinline__ uint packh2(float lo, float hi) {
  __half2 h = __floats2half2_rn(lo, hi);
  uint u;
  __builtin_memcpy(&u, &h, 4);
  return u;
}
__device__ __forceinline__ ushort f2h_us(float f) {
  __half h = __float2half_rn(f);
  ushort us;
  __builtin_memcpy(&us, &h, 2);
  return us;
}
__device__ __forceinline__ float lrelu(float x) {
  return x >= 0.0f ? x : NEG_SLOPE * x;
}

// ---------------------------------------------------------------------------
// W pre-swizzle into MFMA B-fragment order, fp16 (once):
// ---------------------------------------------------------------------------
__global__ void wswz_kernel(const float* __restrict__ W, ushort* __restrict__ Wswz)
{
  int i = blockIdx.x * 256 + threadIdx.x;   // 0..16383
  int j = i & 7, lane = (i >> 3) & 63, nt = (i >> 9) & 7, kt = i >> 12;
  int k = kt * 32 + (lane >> 4) * 8 + j;
  int col = nt * 16 + (lane & 15);
  Wswz[i] = f2h_us(W[k * 128 + col]);
}

// ---------------------------------------------------------------------------
// pois -> fp16 (padded rows zeroed)
// ---------------------------------------------------------------------------
__global__ void poish_kernel(const float* __restrict__ pois,
                             uint4* __restrict__ pois_h, int N_, int NP)
{
  int i = blockIdx.x * 256 + threadIdx.x;   // each = 8 fp16 = one uint4
  if (i >= NP * 16) return;
  int row = i >> 4;
  uint4 o;
  if (row < N_) {
    const float* src = pois + (size_t)i * 8;
    float4 f0 = *(const float4*)src;
    float4 f1 = *(const float4*)(src + 4);
    o.x = packh2(f0.x, f0.y); o.y = packh2(f0.z, f0.w);
    o.z = packh2(f1.x, f1.y); o.w = packh2(f1.z, f1.w);
  } else { o.x = o.y = o.z = o.w = 0; }
  pois_h[i] = o;
}

// ---------------------------------------------------------------------------
// MFMA GEMM (fp16): Y_h = X_h @ W (Wswz pre-swizzled), fused s_n epilogue.
// ---------------------------------------------------------------------------
__global__ __launch_bounds__(256) void gemm_mfma_kernel(
    const ushort* __restrict__ Xb, const ushort* __restrict__ Wswz,
    const float* __restrict__ att, ushort* __restrict__ Yb,
    float* __restrict__ s_n, int rowsN)
{
  __shared__ ushort st[64 * 128];
  int tid = threadIdx.x;
  int w = tid >> 6, lane = tid & 63;
  int q = lane >> 4, c = lane & 15;
  int r0b = blockIdx.x * 64;
  int r0 = r0b + w * 16;
  float4v acc[8];
#pragma unroll
  for (int nt = 0; nt < 8; ++nt) acc[nt] = (float4v){0.f, 0.f, 0.f, 0.f};
  const ushort* arow = Xb + (size_t)(r0 + c) * DIM + q * 8;
#pragma unroll
  for (int kt = 0; kt < 4; ++kt) {
    half8v a = *(const half8v*)(arow + kt * 32);
#pragma unroll
    for (int nt = 0; nt < 8; ++nt) {
      half8v b = *(const half8v*)(Wswz + ((((kt << 3) + nt) << 9) + (lane << 3)));
      acc[nt] = __builtin_amdgcn_mfma_f32_16x16x32_f16(a, b, acc[nt], 0, 0, 0);
    }
  }
  // s_n epilogue: row m = q*4+reg, col = nt*16+c
  float av[8];
#pragma unroll
  for (int nt = 0; nt < 8; ++nt) av[nt] = att[nt * 16 + c];
  float p0 = 0, p1 = 0, p2 = 0, p3 = 0;
#pragma unroll
  for (int nt = 0; nt < 8; ++nt) {
    p0 = fmaf(acc[nt][0], av[nt], p0);
    p1 = fmaf(acc[nt][1], av[nt], p1);
    p2 = fmaf(acc[nt][2], av[nt], p2);
    p3 = fmaf(acc[nt][3], av[nt], p3);
  }
#pragma unroll
  for (int m = 8; m >= 1; m >>= 1) {
    p0 += __shfl_xor(p0, m, 64);
    p1 += __shfl_xor(p1, m, 64);
    p2 += __shfl_xor(p2, m, 64);
    p3 += __shfl_xor(p3, m, 64);
  }
  if (c == 0) {
    int rb = r0 + q * 4;
    if (rb + 0 < rowsN) s_n[rb + 0] = p0;
    if (rb + 1 < rowsN) s_n[rb + 1] = p1;
    if (rb + 2 < rowsN) s_n[rb + 2] = p2;
    if (rb + 3 < rowsN) s_n[rb + 3] = p3;
  }
  // LDS transpose for coalesced fp16 store
  ushort* sw = st + w * 2048;
#pragma unroll
  for (int nt = 0; nt < 8; ++nt) {
    sw[(q * 4 + 0) * 128 + nt * 16 + c] = f2h_us(acc[nt][0]);
    sw[(q * 4 + 1) * 128 + nt * 16 + c] = f2h_us(acc[nt][1]);
    sw[(q * 4 + 2) * 128 + nt * 16 + c] = f2h_us(acc[nt][2]);
    sw[(q * 4 + 3) * 128 + nt * 16 + c] = f2h_us(acc[nt][3]);
  }
  __syncthreads();
#pragma unroll
  for (int it = 0; it < 4; ++it) {
    int idx = tid + it * 256;           // 0..1023 x ushort8
    int row = idx >> 4, seg = idx & 15;
    *(uint4*)(Yb + (size_t)(r0b + row) * DIM + seg * 8) =
        *(const uint4*)&st[row * 128 + seg * 8];
  }
}

// ---------------------------------------------------------------------------
// se_kernel: wv2 = W @ att[D:] (per-block in LDS), s_e + se_hw pack.
// ---------------------------------------------------------------------------
__global__ __launch_bounds__(256) void se_kernel(
    const float* __restrict__ traj, const float* __restrict__ W,
    const float* __restrict__ att, const float* __restrict__ hw,
    float* __restrict__ s_e, float2* __restrict__ se_hw, int M_)
{
  __shared__ float wv[128];
  int tid = threadIdx.x;
  if (tid < 128) {
    const float* wr = W + (size_t)tid * 128;
    float acc = 0.0f;
#pragma unroll 4
    for (int k = 0; k < 128; ++k) acc = fmaf(wr[k], att[DIM + k], acc);
    wv[tid] = acc;
  }
  __syncthreads();
  int e = blockIdx.x * 4 + (tid >> 6);
  int lane = tid & 63;
  if (e >= M_) return;
  const float* row = traj + (size_t)e * DIM;
  float v = row[lane] * wv[lane] + row[lane + 64] * wv[lane + 64];
#pragma unroll
  for (int d = 32; d > 0; d >>= 1) v += __shfl_down(v, d, 64);
  if (lane == 0) {
    s_e[e] = v;
    float2 g; g.x = v; g.y = hw[e];
    se_hw[e] = g;
  }
}

// ---------------------------------------------------------------------------
// LDS-ranked histogram: block (x=chunk, y=bin-subrange). Ranks items of its
// chunk within [base,hi) bins via LDS atomicAdd (no fabric RMWs), dumps the
// per-chunk counts. Replica index for downstream = chunk = j >> chunk_log.
// ---------------------------------------------------------------------------
__global__ __launch_bounds__(256) void hist_lds_kernel(
    const int* __restrict__ idx, int* __restrict__ cnt_r,
    int* __restrict__ rank, int nnz, int nbins, int chunk_log)
{
  __shared__ int h[SUBBINS];
  int t0 = blockIdx.x << chunk_log;
  int t1 = t0 + (1 << chunk_log);
  if (t1 > nnz) t1 = nnz;
  int base = blockIdx.y * SUBBINS;
  int hi = base + SUBBINS;
  if (hi > nbins) hi = nbins;
  for (int i = threadIdx.x; i < SUBBINS; i += 256) h[i] = 0;
  __syncthreads();
  for (int j = t0 + threadIdx.x; j < t1; j += 256) {
    int v = idx[j];
    if (v >= base && v < hi) rank[j] = atomicAdd(&h[v - base], 1);
  }
  __syncthreads();
  for (int i = base + threadIdx.x; i < hi; i += 256)
    cnt_r[(size_t)blockIdx.x * nbins + i] = h[i - base];
}

// ---------------------------------------------------------------------------
// Per-bin exclusive prefix across replicas (in place) + total into cnt.
// ---------------------------------------------------------------------------
__global__ void repsum_kernel(int* __restrict__ cnt_r, int* __restrict__ cnt,
                              int nbins, int reps)
{
  int b = blockIdx.x * blockDim.x + threadIdx.x;
  if (b >= nbins) return;
  int s = 0;
  for (int r = 0; r < reps; ++r) {
    size_t o = (size_t)r * nbins + b;
    int v = cnt_r[o];
    cnt_r[o] = s;
    s += v;
  }
  cnt[b] = s;
}

// ---------------------------------------------------------------------------
// Two-level exclusive scan
// ---------------------------------------------------------------------------
__global__ __launch_bounds__(1024) void scan_block_kernel(
    const int* __restrict__ cnt, int* __restrict__ off,
    int* __restrict__ partials, int nbins)
{
  __shared__ int ws[16];
  int tid = threadIdx.x, lane = tid & 63, wid = tid >> 6;
  int base = blockIdx.x * 4096 + tid * 4;
  int x0 = base + 0 < nbins ? cnt[base + 0] : 0;
  int x1 = base + 1 < nbins ? cnt[base + 1] : 0;
  int x2 = base + 2 < nbins ? cnt[base + 2] : 0;
  int x3 = base + 3 < nbins ? cnt[base + 3] : 0;
  int t = x0 + x1 + x2 + x3;
  int v = t;
#pragma unroll
  for (int d = 1; d < 64; d <<= 1) {
    int y = __shfl_up(v, d, 64);
    if (lane >= d) v += y;
  }
  if (lane == 63) ws[wid] = v;
  __syncthreads();
  if (tid < 16) {
    int s = ws[tid];
#pragma unroll
    for (int d = 1; d < 16; d <<= 1) {
      int y = __shfl_up(s, d, 16);
      if (tid >= d) s += y;
    }
    ws[tid] = s;
  }
  __syncthreads();
  int pre = (wid > 0 ? ws[wid - 1] : 0) + (v - t);
  if (base + 0 < nbins) off[base + 0] = pre;
  if (base + 1 < nbins) off[base + 1] = pre + x0;
  if (base + 2 < nbins) off[base + 2] = pre + x0 + x1;
  if (base + 3 < nbins) off[base + 3] = pre + x0 + x1 + x2;
  if (tid == 0) partials[blockIdx.x] = ws[15];
}

__global__ __launch_bounds__(64) void scan_partials_kernel(
    int* __restrict__ partials, int nb)
{
  int lane = threadIdx.x;
  int t = lane < nb ? partials[lane] : 0;
  int v = t;
#pragma unroll
  for (int d = 1; d < 64; d <<= 1) {
    int y = __shfl_up(v, d, 64);
    if (lane >= d) v += y;
  }
  if (lane < nb) partials[lane] = v - t;
  if (lane == 63) partials[nb] = v;
}

// add block partials into off AND fold the final offsets into the replica
// prefixes so scatter needs only ONE gather: pos = pre[chunk][bin] + local_rank.
__global__ void add_off_combine_kernel(int* __restrict__ off,
                                       const int* __restrict__ partials,
                                       int* __restrict__ pre,
                                       int nbins, int nb, int reps)
{
  int i = blockIdx.x * blockDim.x + threadIdx.x;
  if (i < nbins) {
    int o = off[i] + partials[i >> 12];
    off[i] = o;
    for (int r = 0; r < reps; ++r) pre[(size_t)r * nbins + i] += o;
  }
  if (i == 0) off[nbins] = partials[nb];
}

// ---------------------------------------------------------------------------
// SPLIT atomic-free CSR scatters (chunk-replica combined offsets)
// ---------------------------------------------------------------------------
__global__ void scatter_edge_kernel(const int* __restrict__ node_idx,
                                    const int* __restrict__ edge_idx,
                                    const int* __restrict__ r_e,
                                    const int* __restrict__ pre_e,
                                    int* __restrict__ nd_e, int nnz, int M_)
{
  int j = (blockIdx.x * blockDim.x + threadIdx.x) * 4;
  if (j >= nnz) return;
  if (j + 4 <= nnz) {
    // all 4 items in same chunk (CHUNK_E multiple of 4, j aligned to 4)
    const int* pp = pre_e + (size_t)(j >> CHUNK_E_LOG) * M_;
    int4 e = *(const int4*)&edge_idx[j];
    int4 n = *(const int4*)&node_idx[j];
    int4 re = *(const int4*)&r_e[j];
    nd_e[pp[e.x] + re.x] = n.x;
    nd_e[pp[e.y] + re.y] = n.y;
    nd_e[pp[e.z] + re.z] = n.z;
    nd_e[pp[e.w] + re.w] = n.w;
  } else {
    for (int k = j; k < nnz; ++k) {
      const int* pp = pre_e + (size_t)(k >> CHUNK_E_LOG) * M_;
      nd_e[pp[edge_idx[k]] + r_e[k]] = node_idx[k];
    }
  }
}

__global__ void scatter_node_kernel(const int* __restrict__ node_idx,
                                    const int* __restrict__ edge_idx,
                                    const int* __restrict__ r_n,
                                    const int* __restrict__ pre_n,
                                    int* __restrict__ eidx_n, int nnz, int N_)
{
  int j = (blockIdx.x * blockDim.x + threadIdx.x) * 4;
  if (j >= nnz) return;
  if (j + 4 <= nnz) {
    const int* pp = pre_n + (size_t)(j >> CHUNK_N_LOG) * N_;
    int4 e = *(const int4*)&edge_idx[j];
    int4 n = *(const int4*)&node_idx[j];
    int4 rn = *(const int4*)&r_n[j];
    eidx_n[pp[n.x] + rn.x] = e.x;
    eidx_n[pp[n.y] + rn.y] = e.y;
    eidx_n[pp[n.z] + rn.z] = e.z;
    eidx_n[pp[n.w] + rn.w] = e.w;
  } else {
    for (int k = j; k < nnz; ++k) {
      const int* pp = pre_n + (size_t)(k >> CHUNK_N_LOG) * N_;
      eidx_n[pp[node_idx[k]] + r_n[k]] = edge_idx[k];
    }
  }
}

// ---------------------------------------------------------------------------
// Per-node softmax stats + weighted degree
// ---------------------------------------------------------------------------
__global__ void softstat_kernel(const int* __restrict__ noff,
                                const int* __restrict__ eidx_n,
                                const float* __restrict__ s_n,
                                const float2* __restrict__ se_hw,
                                float2* __restrict__ ns2,
                                float* __restrict__ Dinv, int N_)
{
  int n = blockIdx.x * blockDim.x + threadIdx.x;
  if (n >= N_) return;
  int s = noff[n], e1 = noff[n + 1];
  float sn = s_n[n];
  float m = -INFINITY, den = 0.0f, d = 0.0f;
  int t = s;
  for (; t + 4 <= e1; t += 4) {
    int i0 = eidx_n[t], i1 = eidx_n[t + 1], i2 = eidx_n[t + 2], i3 = eidx_n[t + 3];
    float2 g0 = se_hw[i0], g1 = se_hw[i1], g2 = se_hw[i2], g3 = se_hw[i3];
    float l0 = lrelu(sn + g0.x), l1 = lrelu(sn + g1.x);
    float l2 = lrelu(sn + g2.x), l3 = lrelu(sn + g3.x);
    float mm = fmaxf(fmaxf(fmaxf(l0, l1), fmaxf(l2, l3)), m);
    den = den * __expf(m - mm) + __expf(l0 - mm) + __expf(l1 - mm)
        + __expf(l2 - mm) + __expf(l3 - mm);
    m = mm;
    d += g0.y + g1.y + g2.y + g3.y;
  }
  for (; t < e1; ++t) {
    float2 g = se_hw[eidx_n[t]];
    float l = lrelu(sn + g.x);
    float mm = fmaxf(l, m);
    den = den * __expf(m - mm) + __expf(l - mm);
    m = mm;
    d += g.y;
  }
  if (s == e1) m = 0.0f;
  float2 r;
  r.x = sn;
  r.y = m + __logf(den + 1e-16f);
  ns2[n] = r;
  Dinv[n] = d > 0.0f ? 1.0f / d : 0.0f;
}

// ---------------------------------------------------------------------------
// msg1 WIDE: wave per edge; lane = (row-group r = lane>>4, col-group c = lane&15).
// One uint4 gather instruction covers 4 incidence rows (64 lanes x 16B = 1KB).
// ---------------------------------------------------------------------------
__global__ __launch_bounds__(256) void msg1_kernel(
    const int* __restrict__ eoff, const int* __restrict__ nd_e,
    const float2* __restrict__ ns2, const float* __restrict__ s_e,
    const uint4* __restrict__ xt16, uint4* __restrict__ eo16, int M_)
{
  int e = blockIdx.x * 4 + (threadIdx.x >> 6);
  int lane = threadIdx.x & 63;
  int r = lane >> 4, c = lane & 15;
  if (e >= M_) return;
  int s = eoff[e], t1 = eoff[e + 1];
  int len = t1 - s;
  float binv = len > 0 ? 1.0f / (float)len : 0.0f;
  float se = s_e[e];
  float acc[8];
#pragma unroll
  for (int j = 0; j < 8; ++j) acc[j] = 0.0f;
  for (int t = s; t < t1; t += 8) {
#pragma unroll
    for (int h = 0; h < 2; ++h) {
      int tb = t + h * 4;
      if (tb < t1) {
        int ti = tb + r;
        int tc = ti < t1 ? ti : t1 - 1;
        float valid = ti < t1 ? 1.0f : 0.0f;
        int nd = nd_e[tc];
        float2 q = ns2[nd];
        float coef = valid * __expf(lrelu(q.x + se) - q.y);
        uint4 g = xt16[(size_t)nd * 16 + c];
        float2 f0 = h2f2(g.x), f1 = h2f2(g.y), f2 = h2f2(g.z), f3 = h2f2(g.w);
        acc[0] = fmaf(coef, f0.x, acc[0]);
        acc[1] = fmaf(coef, f0.y, acc[1]);
        acc[2] = fmaf(coef, f1.x, acc[2]);
        acc[3] = fmaf(coef, f1.y, acc[3]);
        acc[4] = fmaf(coef, f2.x, acc[4]);
        acc[5] = fmaf(coef, f2.y, acc[5]);
        acc[6] = fmaf(coef, f3.x, acc[6]);
        acc[7] = fmaf(coef, f3.y, acc[7]);
      }
    }
  }
#pragma unroll
  for (int j = 0; j < 8; ++j) {
    acc[j] += __shfl_xor(acc[j], 16, 64);
    acc[j] += __shfl_xor(acc[j], 32, 64);
  }
  if (r == 0) {
    uint4 o;
    o.x = packh2(acc[0] * binv, acc[1] * binv);
    o.y = packh2(acc[2] * binv, acc[3] * binv);
    o.z = packh2(acc[4] * binv, acc[5] * binv);
    o.w = packh2(acc[6] * binv, acc[7] * binv);
    eo16[(size_t)e * 16 + c] = o;
  }
}

// ---------------------------------------------------------------------------
// msg2 WIDE: same 4-rows-per-gather structure; fp16 residual chain +
// lazy stack-sum epilogue (modes as before), executed by the 16 r==0 lanes.
// ---------------------------------------------------------------------------
__global__ __launch_bounds__(256) void msg2_kernel(
    const int* __restrict__ noff, const int* __restrict__ eidx_n,
    const float2* __restrict__ ns2, const float* __restrict__ Dinv,
    const float* __restrict__ s_e, const uint4* __restrict__ eo16,
    const float* __restrict__ bias,
    const float* __restrict__ cin_f, const uint4* __restrict__ cin_h16,
    const float* __restrict__ x1f, const uint4* __restrict__ x2h16,
    uint4* __restrict__ couth16, float* __restrict__ dout,
    int mode, int N_)
{
  int n = blockIdx.x * 4 + (threadIdx.x >> 6);
  int lane = threadIdx.x & 63;
  int r = lane >> 4, c = lane & 15;
  if (n >= N_) return;
  int s = noff[n], t1 = noff[n + 1];
  float2 nsv = ns2[n];
  float sn = nsv.x, lz = nsv.y;
  float acc[8];
#pragma unroll
  for (int j = 0; j < 8; ++j) acc[j] = 0.0f;
  for (int t = s; t < t1; t += 8) {
#pragma unroll
    for (int h = 0; h < 2; ++h) {
      int tb = t + h * 4;
      if (tb < t1) {
        int ti = tb + r;
        int tc = ti < t1 ? ti : t1 - 1;
        float valid = ti < t1 ? 1.0f : 0.0f;
        int ed = eidx_n[tc];
        float xs = s_e[ed];
        float coef = valid * __expf(lrelu(sn + xs) - lz);
        uint4 g = eo16[(size_t)ed * 16 + c];
        float2 f0 = h2f2(g.x), f1 = h2f2(g.y), f2 = h2f2(g.z), f3 = h2f2(g.w);
        acc[0] = fmaf(coef, f0.x, acc[0]);
        acc[1] = fmaf(coef, f0.y, acc[1]);
        acc[2] = fmaf(coef, f1.x, acc[2]);
        acc[3] = fmaf(coef, f1.y, acc[3]);
        acc[4] = fmaf(coef, f2.x, acc[4]);
        acc[5] = fmaf(coef, f2.y, acc[5]);
        acc[6] = fmaf(coef, f3.x, acc[6]);
        acc[7] = fmaf(coef, f3.y, acc[7]);
      }
    }
  }
#pragma unroll
  for (int j = 0; j < 8; ++j) {
    acc[j] += __shfl_xor(acc[j], 16, 64);
    acc[j] += __shfl_xor(acc[j], 32, 64);
  }
  if (r != 0) return;
  float sc = Dinv[n];
  // cin (8 cols starting at c*8)
  float cin[8];
  if (mode == 0) {
    const float4* cf = (const float4*)(cin_f + (size_t)n * DIM);
    float4 a = cf[c * 2], b = cf[c * 2 + 1];
    cin[0] = a.x; cin[1] = a.y; cin[2] = a.z; cin[3] = a.w;
    cin[4] = b.x; cin[5] = b.y; cin[6] = b.z; cin[7] = b.w;
  } else {
    uint4 ch = cin_h16[(size_t)n * 16 + c];
    float2 p0 = h2f2(ch.x), p1 = h2f2(ch.y), p2 = h2f2(ch.z), p3 = h2f2(ch.w);
    cin[0] = p0.x; cin[1] = p0.y; cin[2] = p1.x; cin[3] = p1.y;
    cin[4] = p2.x; cin[5] = p2.y; cin[6] = p3.x; cin[7] = p3.y;
  }
  const float4* bf = (const float4*)bias;
  float4 ba = bf[c * 2], bb = bf[c * 2 + 1];
  float bs[8] = {ba.x, ba.y, ba.z, ba.w, bb.x, bb.y, bb.z, bb.w};
  float cx[8];
#pragma unroll
  for (int j = 0; j < 8; ++j) cx[j] = cin[j] + acc[j] * sc + bs[j];
  if (mode == 2) {
    const float4* x1 = (const float4*)(x1f + (size_t)n * DIM);
    float4 xa = x1[c * 2], xb = x1[c * 2 + 1];
    float x1v[8] = {xa.x, xa.y, xa.z, xa.w, xb.x, xb.y, xb.z, xb.w};
    uint4 x2 = x2h16[(size_t)n * 16 + c];
    float2 y0 = h2f2(x2.x), y1 = h2f2(x2.y), y2 = h2f2(x2.z), y3 = h2f2(x2.w);
    float x2v[8] = {y0.x, y0.y, y1.x, y1.y, y2.x, y2.y, y3.x, y3.y};
    float4 o0, o1;
    o0.x = (x1v[0] + x2v[0] + cin[0] + cx[0]) * 0.25f;
    o0.y = (x1v[1] + x2v[1] + cin[1] + cx[1]) * 0.25f;
    o0.z = (x1v[2] + x2v[2] + cin[2] + cx[2]) * 0.25f;
    o0.w = (x1v[3] + x2v[3] + cin[3] + cx[3]) * 0.25f;
    o1.x = (x1v[4] + x2v[4] + cin[4] + cx[4]) * 0.25f;
    o1.y = (x1v[5] + x2v[5] + cin[5] + cx[5]) * 0.25f;
    o1.z = (x1v[6] + x2v[6] + cin[6] + cx[6]) * 0.25f;
    o1.w = (x1v[7] + x2v[7] + cin[7] + cx[7]) * 0.25f;
    float4* dp = (float4*)(dout + (size_t)n * DIM);
    dp[c * 2] = o0;
    dp[c * 2 + 1] = o1;
  } else {
    uint4 o;
    o.x = packh2(cx[0], cx[1]);
    o.y = packh2(cx[2], cx[3]);
    o.z = packh2(cx[4], cx[5]);
    o.w = packh2(cx[6], cx[7]);
    couth16[(size_t)n * 16 + c] = o;
  }
}

// ---------------------------------------------------------------------------
static inline int cdiv(int a, int b) { return (a + b - 1) / b; }

extern "C" void kernel_launch(void* const* d_in, const int* in_sizes, int n_in,
                              void* d_out, int out_size, void* d_ws, size_t ws_size,
                              hipStream_t stream)
{
  const float* pois = (const float*)d_in[0];
  const float* traj = (const float*)d_in[1];
  const float* hw   = (const float*)d_in[2];
  const int* node_idx = (const int*)d_in[3];
  const int* edge_idx = (const int*)d_in[4];
  const float* W    = (const float*)d_in[5];
  const float* att  = (const float*)d_in[6];
  const float* bias = (const float*)d_in[7];
  float* dout = (float*)d_out;

  const int N   = in_sizes[0] / DIM;
  const int M   = in_sizes[2];
  const int NNZ = in_sizes[3];
  const int NP  = (N + 63) & ~63;   // row-padded for 64-row MFMA tiles
  const int NBE = cdiv(NNZ, 1 << CHUNK_E_LOG);   // edge chunks
  const int NBN = cdiv(NNZ, 1 << CHUNK_N_LOG);   // node chunks

  char* p = (char*)d_ws;
  auto alloc = [&](size_t bytes) -> void* {
    void* r = (void*)p;
    p += (bytes + 255) & ~(size_t)255;
    return r;
  };
  ushort* xt_h    = (ushort*)alloc((size_t)NP * DIM * 2);
  ushort* pois_h  = (ushort*)alloc((size_t)NP * DIM * 2);
  uint*   cura_h  = (uint*)alloc((size_t)NP * 64 * 4);   // cur1 fp16
  uint*   curb_h  = (uint*)alloc((size_t)NP * 64 * 4);   // cur2 fp16
  ushort* W_swz   = (ushort*)alloc(16384 * 2);
  uint*   eo_h  = (uint*)alloc((size_t)M * (DIM / 2) * 4);
  float2* ns2   = (float2*)alloc((size_t)N * 8);
  float*  s_e  = (float*)alloc((size_t)M * 4);
  float2* se_hw = (float2*)alloc((size_t)M * 8);
  float*  s_n  = (float*)alloc((size_t)N * 4);
  float*  Dinv = (float*)alloc((size_t)N * 4);
  int* ecnt   = (int*)alloc((size_t)M * 4);
  int* ncnt   = (int*)alloc((size_t)N * 4);
  int* ecnt_r = (int*)alloc((size_t)NBE * M * 4);   // per-chunk counters / prefixes
  int* ncnt_r = (int*)alloc((size_t)NBN * N * 4);
  int* eoff = (int*)alloc((size_t)(M + 1) * 4);
  int* noff = (int*)alloc((size_t)(N + 1) * 4);
  int* r_e  = (int*)alloc((size_t)NNZ * 4);
  int* r_n  = (int*)alloc((size_t)NNZ * 4);
  int* nd_e   = (int*)alloc((size_t)NNZ * 4);
  int* eidx_n = (int*)alloc((size_t)NNZ * 4);
  int* part_e = (int*)alloc(65 * 4);
  int* part_n = (int*)alloc(65 * 4);
  (void)ws_size;

  const int nbE = cdiv(M, 4096), nbN = cdiv(N, 4096);

  // ---- incidence structure (layer-invariant), LDS-ranked (no fabric RMWs) ----
  hist_lds_kernel<<<dim3(NBE, cdiv(M, SUBBINS)), 256, 0, stream>>>(
      edge_idx, ecnt_r, r_e, NNZ, M, CHUNK_E_LOG);
  hist_lds_kernel<<<dim3(NBN, cdiv(N, SUBBINS)), 256, 0, stream>>>(
      node_idx, ncnt_r, r_n, NNZ, N, CHUNK_N_LOG);
  repsum_kernel<<<cdiv(M, 256), 256, 0, stream>>>(ecnt_r, ecnt, M, NBE);
  repsum_kernel<<<cdiv(N, 256), 256, 0, stream>>>(ncnt_r, ncnt, N, NBN);
  scan_block_kernel<<<nbE, 1024, 0, stream>>>(ecnt, eoff, part_e, M);
  scan_block_kernel<<<nbN, 1024, 0, stream>>>(ncnt, noff, part_n, N);
  scan_partials_kernel<<<1, 64, 0, stream>>>(part_e, nbE);
  scan_partials_kernel<<<1, 64, 0, stream>>>(part_n, nbN);
  add_off_combine_kernel<<<cdiv(M, 256), 256, 0, stream>>>(eoff, part_e, ecnt_r, M, nbE, NBE);
  add_off_combine_kernel<<<cdiv(N, 256), 256, 0, stream>>>(noff, part_n, ncnt_r, N, nbN, NBN);
  scatter_edge_kernel<<<cdiv(NNZ, 1024), 256, 0, stream>>>(node_idx, edge_idx, r_e, ecnt_r, nd_e, NNZ, M);
  scatter_node_kernel<<<cdiv(NNZ, 1024), 256, 0, stream>>>(node_idx, edge_idx, r_n, ncnt_r, eidx_n, NNZ, N);

  // ---- layer-invariant dense prep ----
  wswz_kernel<<<64, 256, 0, stream>>>(W, W_swz);
  se_kernel<<<cdiv(M, 4), 256, 0, stream>>>(traj, W, att, hw, s_e, se_hw, M);
  poish_kernel<<<cdiv(NP * 16, 256), 256, 0, stream>>>(pois, (uint4*)pois_h, N, NP);

  // ---- layers ----
  // L0: gemm(pois_h); msg2 mode0: cin=pois fp32 -> cura_h
  // L1: gemm(cura_h); msg2 mode1: cin=cura_h   -> curb_h
  // L2: gemm(curb_h); msg2 mode2: cin=curb_h, x1=pois, x2=cura_h -> dout
  for (int layer = 0; layer < 3; ++layer) {
    const ushort* gin = (layer == 0) ? pois_h
                       : (layer == 1) ? (const ushort*)cura_h
                                      : (const ushort*)curb_h;
    gemm_mfma_kernel<<<NP / 64, 256, 0, stream>>>(gin, W_swz, att, xt_h, s_n, N);
    softstat_kernel<<<cdiv(N, 256), 256, 0, stream>>>(noff, eidx_n, s_n, se_hw, ns2, Dinv, N);
    msg1_kernel<<<cdiv(M, 4), 256, 0, stream>>>(eoff, nd_e, ns2, s_e,
                                                (const uint4*)xt_h, (uint4*)eo_h, M);
    const uint* cin_h = (layer == 1) ? cura_h : curb_h;   // unused in mode 0
    uint* couth = (layer == 0) ? cura_h : curb_h;
    msg2_kernel<<<cdiv(N, 4), 256, 0, stream>>>(noff, eidx_n, ns2, Dinv, s_e,
                                                (const uint4*)eo_h, bias,
                                                pois, (const uint4*)cin_h,
                                                pois, (const uint4*)cura_h,
                                                (uint4*)couth, dout, layer, N);
  }
}

// Round 11
// 689.487 us; speedup vs baseline: 1.0950x; 1.0950x over previous
//
#include <hip/hip_runtime.h>
#include <hip/hip_fp16.h>
#include <cstdint>
#include <cstddef>
#include <cstring>

#define DIM 128
#define NEG_SLOPE 0.2f

#define EREP 16   // replicas for edge counters
#define NREP 8    // replicas for node counters

typedef _Float16 half8v __attribute__((ext_vector_type(8)));
typedef __attribute__((ext_vector_type(4))) float float4v;

// ---- fp16 helpers ----------------------------------------------------------
__device__ __forceinline__ float2 h2f2(uint u) {
  __half2 h;
  __builtin_memcpy(&h, &u, 4);
  return __half22float2(h);
}
__device__ __forceinline__ uint packh2(float lo, float hi) {
  __half2 h = __floats2half2_rn(lo, hi);
  uint u;
  __builtin_memcpy(&u, &h, 4);
  return u;
}
__device__ __forceinline__ ushort f2h_us(float f) {
  __half h = __float2half_rn(f);
  ushort us;
  __builtin_memcpy(&us, &h, 2);
  return us;
}
__device__ __forceinline__ float lrelu(float x) {
  return x >= 0.0f ? x : NEG_SLOPE * x;
}

// ---------------------------------------------------------------------------
// W pre-swizzle into MFMA B-fragment order, fp16 (once):
// ---------------------------------------------------------------------------
__global__ void wswz_kernel(const float* __restrict__ W, ushort* __restrict__ Wswz)
{
  int i = blockIdx.x * 256 + threadIdx.x;   // 0..16383
  int j = i & 7, lane = (i >> 3) & 63, nt = (i >> 9) & 7, kt = i >> 12;
  int k = kt * 32 + (lane >> 4) * 8 + j;
  int col = nt * 16 + (lane & 15);
  Wswz[i] = f2h_us(W[k * 128 + col]);
}

// ---------------------------------------------------------------------------
// pois -> fp16 (padded rows zeroed)
// ---------------------------------------------------------------------------
__global__ void poish_kernel(const float* __restrict__ pois,
                             uint4* __restrict__ pois_h, int N_, int NP)
{
  int i = blockIdx.x * 256 + threadIdx.x;   // each = 8 fp16 = one uint4
  if (i >= NP * 16) return;
  int row = i >> 4;
  uint4 o;
  if (row < N_) {
    const float* src = pois + (size_t)i * 8;
    float4 f0 = *(const float4*)src;
    float4 f1 = *(const float4*)(src + 4);
    o.x = packh2(f0.x, f0.y); o.y = packh2(f0.z, f0.w);
    o.z = packh2(f1.x, f1.y); o.w = packh2(f1.z, f1.w);
  } else { o.x = o.y = o.z = o.w = 0; }
  pois_h[i] = o;
}

// ---------------------------------------------------------------------------
// MFMA GEMM (fp16): Y_h = X_h @ W (Wswz pre-swizzled), fused s_n epilogue.
// ---------------------------------------------------------------------------
__global__ __launch_bounds__(256) void gemm_mfma_kernel(
    const ushort* __restrict__ Xb, const ushort* __restrict__ Wswz,
    const float* __restrict__ att, ushort* __restrict__ Yb,
    float* __restrict__ s_n, int rowsN)
{
  __shared__ ushort st[64 * 128];
  int tid = threadIdx.x;
  int w = tid >> 6, lane = tid & 63;
  int q = lane >> 4, c = lane & 15;
  int r0b = blockIdx.x * 64;
  int r0 = r0b + w * 16;
  float4v acc[8];
#pragma unroll
  for (int nt = 0; nt < 8; ++nt) acc[nt] = (float4v){0.f, 0.f, 0.f, 0.f};
  const ushort* arow = Xb + (size_t)(r0 + c) * DIM + q * 8;
#pragma unroll
  for (int kt = 0; kt < 4; ++kt) {
    half8v a = *(const half8v*)(arow + kt * 32);
#pragma unroll
    for (int nt = 0; nt < 8; ++nt) {
      half8v b = *(const half8v*)(Wswz + ((((kt << 3) + nt) << 9) + (lane << 3)));
      acc[nt] = __builtin_amdgcn_mfma_f32_16x16x32_f16(a, b, acc[nt], 0, 0, 0);
    }
  }
  // s_n epilogue: row m = q*4+reg, col = nt*16+c
  float av[8];
#pragma unroll
  for (int nt = 0; nt < 8; ++nt) av[nt] = att[nt * 16 + c];
  float p0 = 0, p1 = 0, p2 = 0, p3 = 0;
#pragma unroll
  for (int nt = 0; nt < 8; ++nt) {
    p0 = fmaf(acc[nt][0], av[nt], p0);
    p1 = fmaf(acc[nt][1], av[nt], p1);
    p2 = fmaf(acc[nt][2], av[nt], p2);
    p3 = fmaf(acc[nt][3], av[nt], p3);
  }
#pragma unroll
  for (int m = 8; m >= 1; m >>= 1) {
    p0 += __shfl_xor(p0, m, 64);
    p1 += __shfl_xor(p1, m, 64);
    p2 += __shfl_xor(p2, m, 64);
    p3 += __shfl_xor(p3, m, 64);
  }
  if (c == 0) {
    int rb = r0 + q * 4;
    if (rb + 0 < rowsN) s_n[rb + 0] = p0;
    if (rb + 1 < rowsN) s_n[rb + 1] = p1;
    if (rb + 2 < rowsN) s_n[rb + 2] = p2;
    if (rb + 3 < rowsN) s_n[rb + 3] = p3;
  }
  // LDS transpose for coalesced fp16 store
  ushort* sw = st + w * 2048;
#pragma unroll
  for (int nt = 0; nt < 8; ++nt) {
    sw[(q * 4 + 0) * 128 + nt * 16 + c] = f2h_us(acc[nt][0]);
    sw[(q * 4 + 1) * 128 + nt * 16 + c] = f2h_us(acc[nt][1]);
    sw[(q * 4 + 2) * 128 + nt * 16 + c] = f2h_us(acc[nt][2]);
    sw[(q * 4 + 3) * 128 + nt * 16 + c] = f2h_us(acc[nt][3]);
  }
  __syncthreads();
#pragma unroll
  for (int it = 0; it < 4; ++it) {
    int idx = tid + it * 256;           // 0..1023 x ushort8
    int row = idx >> 4, seg = idx & 15;
    *(uint4*)(Yb + (size_t)(r0b + row) * DIM + seg * 8) =
        *(const uint4*)&st[row * 128 + seg * 8];
  }
}

// ---------------------------------------------------------------------------
// se_kernel: wv2 = W @ att[D:] (per-block in LDS), s_e + se_hw pack.
// ---------------------------------------------------------------------------
__global__ __launch_bounds__(256) void se_kernel(
    const float* __restrict__ traj, const float* __restrict__ W,
    const float* __restrict__ att, const float* __restrict__ hw,
    float* __restrict__ s_e, float2* __restrict__ se_hw, int M_)
{
  __shared__ float wv[128];
  int tid = threadIdx.x;
  if (tid < 128) {
    const float* wr = W + (size_t)tid * 128;
    float acc = 0.0f;
#pragma unroll 4
    for (int k = 0; k < 128; ++k) acc = fmaf(wr[k], att[DIM + k], acc);
    wv[tid] = acc;
  }
  __syncthreads();
  int e = blockIdx.x * 4 + (tid >> 6);
  int lane = tid & 63;
  if (e >= M_) return;
  const float* row = traj + (size_t)e * DIM;
  float v = row[lane] * wv[lane] + row[lane + 64] * wv[lane + 64];
#pragma unroll
  for (int d = 32; d > 0; d >>= 1) v += __shfl_down(v, d, 64);
  if (lane == 0) {
    s_e[e] = v;
    float2 g; g.x = v; g.y = hw[e];
    se_hw[e] = g;
  }
}

// ---------------------------------------------------------------------------
// Rank-fused histogram with REPLICATED counters.
// ---------------------------------------------------------------------------
__global__ void hist_rank_kernel(const int* __restrict__ node_idx,
                                 const int* __restrict__ edge_idx,
                                 int* __restrict__ ncnt_r, int* __restrict__ ecnt_r,
                                 int* __restrict__ r_n, int* __restrict__ r_e,
                                 int nnz, int M_, int N_)
{
  int t = blockIdx.x * blockDim.x + threadIdx.x;
  int j = t * 2;
  if (j >= nnz) return;
  int* ec = ecnt_r + (size_t)(t & (EREP - 1)) * M_;
  int* nc = ncnt_r + (size_t)(t & (NREP - 1)) * N_;
  if (j + 2 <= nnz) {
    int2 e = *(const int2*)&edge_idx[j];
    int2 n = *(const int2*)&node_idx[j];
    int a0 = atomicAdd(&ec[e.x], 1);
    int a1 = atomicAdd(&ec[e.y], 1);
    int b0 = atomicAdd(&nc[n.x], 1);
    int b1 = atomicAdd(&nc[n.y], 1);
    *(int2*)&r_e[j] = make_int2(a0, a1);
    *(int2*)&r_n[j] = make_int2(b0, b1);
  } else {
    r_e[j] = atomicAdd(&ec[edge_idx[j]], 1);
    r_n[j] = atomicAdd(&nc[node_idx[j]], 1);
  }
}

// ---------------------------------------------------------------------------
// Per-bin exclusive prefix across replicas (in place) + total into cnt.
// ---------------------------------------------------------------------------
__global__ void repsum_kernel(int* __restrict__ cnt_r, int* __restrict__ cnt,
                              int nbins, int reps)
{
  int b = blockIdx.x * blockDim.x + threadIdx.x;
  if (b >= nbins) return;
  int s = 0;
  for (int r = 0; r < reps; ++r) {
    size_t o = (size_t)r * nbins + b;
    int v = cnt_r[o];
    cnt_r[o] = s;
    s += v;
  }
  cnt[b] = s;
}

// ---------------------------------------------------------------------------
// Two-level exclusive scan
// ---------------------------------------------------------------------------
__global__ __launch_bounds__(1024) void scan_block_kernel(
    const int* __restrict__ cnt, int* __restrict__ off,
    int* __restrict__ partials, int nbins)
{
  __shared__ int ws[16];
  int tid = threadIdx.x, lane = tid & 63, wid = tid >> 6;
  int base = blockIdx.x * 4096 + tid * 4;
  int x0 = base + 0 < nbins ? cnt[base + 0] : 0;
  int x1 = base + 1 < nbins ? cnt[base + 1] : 0;
  int x2 = base + 2 < nbins ? cnt[base + 2] : 0;
  int x3 = base + 3 < nbins ? cnt[base + 3] : 0;
  int t = x0 + x1 + x2 + x3;
  int v = t;
#pragma unroll
  for (int d = 1; d < 64; d <<= 1) {
    int y = __shfl_up(v, d, 64);
    if (lane >= d) v += y;
  }
  if (lane == 63) ws[wid] = v;
  __syncthreads();
  if (tid < 16) {
    int s = ws[tid];
#pragma unroll
    for (int d = 1; d < 16; d <<= 1) {
      int y = __shfl_up(s, d, 16);
      if (tid >= d) s += y;
    }
    ws[tid] = s;
  }
  __syncthreads();
  int pre = (wid > 0 ? ws[wid - 1] : 0) + (v - t);
  if (base + 0 < nbins) off[base + 0] = pre;
  if (base + 1 < nbins) off[base + 1] = pre + x0;
  if (base + 2 < nbins) off[base + 2] = pre + x0 + x1;
  if (base + 3 < nbins) off[base + 3] = pre + x0 + x1 + x2;
  if (tid == 0) partials[blockIdx.x] = ws[15];
}

__global__ __launch_bounds__(64) void scan_partials_kernel(
    int* __restrict__ partials, int nb)
{
  int lane = threadIdx.x;
  int t = lane < nb ? partials[lane] : 0;
  int v = t;
#pragma unroll
  for (int d = 1; d < 64; d <<= 1) {
    int y = __shfl_up(v, d, 64);
    if (lane >= d) v += y;
  }
  if (lane < nb) partials[lane] = v - t;
  if (lane == 63) partials[nb] = v;
}

// add block partials into off AND fold the final offsets into the replica
// prefixes so scatter needs only ONE gather: pos = pre[rep][bin] + local_rank.
__global__ void add_off_combine_kernel(int* __restrict__ off,
                                       const int* __restrict__ partials,
                                       int* __restrict__ pre,
                                       int nbins, int nb, int reps)
{
  int i = blockIdx.x * blockDim.x + threadIdx.x;
  if (i < nbins) {
    int o = off[i] + partials[i >> 12];
    off[i] = o;
    for (int r = 0; r < reps; ++r) pre[(size_t)r * nbins + i] += o;
  }
  if (i == 0) off[nbins] = partials[nb];
}

// ---------------------------------------------------------------------------
// SPLIT atomic-free CSR scatters (replica-aware combined offsets)
// ---------------------------------------------------------------------------
__global__ void scatter_edge_kernel(const int* __restrict__ node_idx,
                                    const int* __restrict__ edge_idx,
                                    const int* __restrict__ r_e,
                                    const int* __restrict__ pre_e,
                                    int* __restrict__ nd_e, int nnz, int M_)
{
  int j = (blockIdx.x * blockDim.x + threadIdx.x) * 4;
  if (j >= nnz) return;
  if (j + 4 <= nnz) {
    // items j,j+1 came from hist-thread (j>>1); items j+2,j+3 from (j>>1)+1
    const int* p0 = pre_e + (size_t)((j >> 1) & (EREP - 1)) * M_;
    const int* p1 = pre_e + (size_t)(((j >> 1) + 1) & (EREP - 1)) * M_;
    int4 e = *(const int4*)&edge_idx[j];
    int4 n = *(const int4*)&node_idx[j];
    int4 re = *(const int4*)&r_e[j];
    nd_e[p0[e.x] + re.x] = n.x;
    nd_e[p0[e.y] + re.y] = n.y;
    nd_e[p1[e.z] + re.z] = n.z;
    nd_e[p1[e.w] + re.w] = n.w;
  } else {
    for (int k = j; k < nnz; ++k) {
      const int* pp = pre_e + (size_t)((k >> 1) & (EREP - 1)) * M_;
      nd_e[pp[edge_idx[k]] + r_e[k]] = node_idx[k];
    }
  }
}

__global__ void scatter_node_kernel(const int* __restrict__ node_idx,
                                    const int* __restrict__ edge_idx,
                                    const int* __restrict__ r_n,
                                    const int* __restrict__ pre_n,
                                    int* __restrict__ eidx_n, int nnz, int N_)
{
  int j = (blockIdx.x * blockDim.x + threadIdx.x) * 4;
  if (j >= nnz) return;
  if (j + 4 <= nnz) {
    const int* p0 = pre_n + (size_t)((j >> 1) & (NREP - 1)) * N_;
    const int* p1 = pre_n + (size_t)(((j >> 1) + 1) & (NREP - 1)) * N_;
    int4 e = *(const int4*)&edge_idx[j];
    int4 n = *(const int4*)&node_idx[j];
    int4 rn = *(const int4*)&r_n[j];
    eidx_n[p0[n.x] + rn.x] = e.x;
    eidx_n[p0[n.y] + rn.y] = e.y;
    eidx_n[p1[n.z] + rn.z] = e.z;
    eidx_n[p1[n.w] + rn.w] = e.w;
  } else {
    for (int k = j; k < nnz; ++k) {
      const int* pp = pre_n + (size_t)((k >> 1) & (NREP - 1)) * N_;
      eidx_n[pp[node_idx[k]] + r_n[k]] = edge_idx[k];
    }
  }
}

// ---------------------------------------------------------------------------
// Per-node softmax stats + weighted degree
// ---------------------------------------------------------------------------
__global__ void softstat_kernel(const int* __restrict__ noff,
                                const int* __restrict__ eidx_n,
                                const float* __restrict__ s_n,
                                const float2* __restrict__ se_hw,
                                float2* __restrict__ ns2,
                                float* __restrict__ Dinv, int N_)
{
  int n = blockIdx.x * blockDim.x + threadIdx.x;
  if (n >= N_) return;
  int s = noff[n], e1 = noff[n + 1];
  float sn = s_n[n];
  float m = -INFINITY, den = 0.0f, d = 0.0f;
  int t = s;
  for (; t + 4 <= e1; t += 4) {
    int i0 = eidx_n[t], i1 = eidx_n[t + 1], i2 = eidx_n[t + 2], i3 = eidx_n[t + 3];
    float2 g0 = se_hw[i0], g1 = se_hw[i1], g2 = se_hw[i2], g3 = se_hw[i3];
    float l0 = lrelu(sn + g0.x), l1 = lrelu(sn + g1.x);
    float l2 = lrelu(sn + g2.x), l3 = lrelu(sn + g3.x);
    float mm = fmaxf(fmaxf(fmaxf(l0, l1), fmaxf(l2, l3)), m);
    den = den * __expf(m - mm) + __expf(l0 - mm) + __expf(l1 - mm)
        + __expf(l2 - mm) + __expf(l3 - mm);
    m = mm;
    d += g0.y + g1.y + g2.y + g3.y;
  }
  for (; t < e1; ++t) {
    float2 g = se_hw[eidx_n[t]];
    float l = lrelu(sn + g.x);
    float mm = fmaxf(l, m);
    den = den * __expf(m - mm) + __expf(l - mm);
    m = mm;
    d += g.y;
  }
  if (s == e1) m = 0.0f;
  float2 r;
  r.x = sn;
  r.y = m + __logf(den + 1e-16f);
  ns2[n] = r;
  Dinv[n] = d > 0.0f ? 1.0f / d : 0.0f;
}

// ---------------------------------------------------------------------------
// msg1 WIDE: wave per edge; lane = (row-group r = lane>>4, col-group c = lane&15).
// One uint4 gather instruction covers 4 incidence rows (64 lanes x 16B = 1KB).
// ---------------------------------------------------------------------------
__global__ __launch_bounds__(256) void msg1_kernel(
    const int* __restrict__ eoff, const int* __restrict__ nd_e,
    const float2* __restrict__ ns2, const float* __restrict__ s_e,
    const uint4* __restrict__ xt16, uint4* __restrict__ eo16, int M_)
{
  int e = blockIdx.x * 4 + (threadIdx.x >> 6);
  int lane = threadIdx.x & 63;
  int r = lane >> 4, c = lane & 15;
  if (e >= M_) return;
  int s = eoff[e], t1 = eoff[e + 1];
  int len = t1 - s;
  float binv = len > 0 ? 1.0f / (float)len : 0.0f;
  float se = s_e[e];
  float acc[8];
#pragma unroll
  for (int j = 0; j < 8; ++j) acc[j] = 0.0f;
  for (int t = s; t < t1; t += 8) {
#pragma unroll
    for (int h = 0; h < 2; ++h) {
      int tb = t + h * 4;
      if (tb < t1) {
        int ti = tb + r;
        int tc = ti < t1 ? ti : t1 - 1;
        float valid = ti < t1 ? 1.0f : 0.0f;
        int nd = nd_e[tc];
        float2 q = ns2[nd];
        float coef = valid * __expf(lrelu(q.x + se) - q.y);
        uint4 g = xt16[(size_t)nd * 16 + c];
        float2 f0 = h2f2(g.x), f1 = h2f2(g.y), f2 = h2f2(g.z), f3 = h2f2(g.w);
        acc[0] = fmaf(coef, f0.x, acc[0]);
        acc[1] = fmaf(coef, f0.y, acc[1]);
        acc[2] = fmaf(coef, f1.x, acc[2]);
        acc[3] = fmaf(coef, f1.y, acc[3]);
        acc[4] = fmaf(coef, f2.x, acc[4]);
        acc[5] = fmaf(coef, f2.y, acc[5]);
        acc[6] = fmaf(coef, f3.x, acc[6]);
        acc[7] = fmaf(coef, f3.y, acc[7]);
      }
    }
  }
#pragma unroll
  for (int j = 0; j < 8; ++j) {
    acc[j] += __shfl_xor(acc[j], 16, 64);
    acc[j] += __shfl_xor(acc[j], 32, 64);
  }
  if (r == 0) {
    uint4 o;
    o.x = packh2(acc[0] * binv, acc[1] * binv);
    o.y = packh2(acc[2] * binv, acc[3] * binv);
    o.z = packh2(acc[4] * binv, acc[5] * binv);
    o.w = packh2(acc[6] * binv, acc[7] * binv);
    eo16[(size_t)e * 16 + c] = o;
  }
}

// ---------------------------------------------------------------------------
// msg2 WIDE: same 4-rows-per-gather structure; fp16 residual chain +
// lazy stack-sum epilogue, executed by the 16 r==0 lanes.
//  mode 0: cin = fp32 pois;  out = cur_h
//  mode 1: cin = fp16 cin_h; out = cur_h
//  mode 2: cin = fp16 cin_h; dout = 0.25*(h(x1h) + h(x2h) + cin + cx)
//          (x1h = fp16 pois mirror; terminal sum term, error *0.25 only)
// ---------------------------------------------------------------------------
__global__ __launch_bounds__(256) void msg2_kernel(
    const int* __restrict__ noff, const int* __restrict__ eidx_n,
    const float2* __restrict__ ns2, const float* __restrict__ Dinv,
    const float* __restrict__ s_e, const uint4* __restrict__ eo16,
    const float* __restrict__ bias,
    const float* __restrict__ cin_f, const uint4* __restrict__ cin_h16,
    const uint4* __restrict__ x1h16, const uint4* __restrict__ x2h16,
    uint4* __restrict__ couth16, float* __restrict__ dout,
    int mode, int N_)
{
  int n = blockIdx.x * 4 + (threadIdx.x >> 6);
  int lane = threadIdx.x & 63;
  int r = lane >> 4, c = lane & 15;
  if (n >= N_) return;
  int s = noff[n], t1 = noff[n + 1];
  float2 nsv = ns2[n];
  float sn = nsv.x, lz = nsv.y;
  float acc[8];
#pragma unroll
  for (int j = 0; j < 8; ++j) acc[j] = 0.0f;
  for (int t = s; t < t1; t += 8) {
#pragma unroll
    for (int h = 0; h < 2; ++h) {
      int tb = t + h * 4;
      if (tb < t1) {
        int ti = tb + r;
        int tc = ti < t1 ? ti : t1 - 1;
        float valid = ti < t1 ? 1.0f : 0.0f;
        int ed = eidx_n[tc];
        float xs = s_e[ed];
        float coef = valid * __expf(lrelu(sn + xs) - lz);
        uint4 g = eo16[(size_t)ed * 16 + c];
        float2 f0 = h2f2(g.x), f1 = h2f2(g.y), f2 = h2f2(g.z), f3 = h2f2(g.w);
        acc[0] = fmaf(coef, f0.x, acc[0]);
        acc[1] = fmaf(coef, f0.y, acc[1]);
        acc[2] = fmaf(coef, f1.x, acc[2]);
        acc[3] = fmaf(coef, f1.y, acc[3]);
        acc[4] = fmaf(coef, f2.x, acc[4]);
        acc[5] = fmaf(coef, f2.y, acc[5]);
        acc[6] = fmaf(coef, f3.x, acc[6]);
        acc[7] = fmaf(coef, f3.y, acc[7]);
      }
    }
  }
#pragma unroll
  for (int j = 0; j < 8; ++j) {
    acc[j] += __shfl_xor(acc[j], 16, 64);
    acc[j] += __shfl_xor(acc[j], 32, 64);
  }
  if (r != 0) return;
  float sc = Dinv[n];
  // cin (8 cols starting at c*8)
  float cin[8];
  if (mode == 0) {
    const float4* cf = (const float4*)(cin_f + (size_t)n * DIM);
    float4 a = cf[c * 2], b = cf[c * 2 + 1];
    cin[0] = a.x; cin[1] = a.y; cin[2] = a.z; cin[3] = a.w;
    cin[4] = b.x; cin[5] = b.y; cin[6] = b.z; cin[7] = b.w;
  } else {
    uint4 ch = cin_h16[(size_t)n * 16 + c];
    float2 p0 = h2f2(ch.x), p1 = h2f2(ch.y), p2 = h2f2(ch.z), p3 = h2f2(ch.w);
    cin[0] = p0.x; cin[1] = p0.y; cin[2] = p1.x; cin[3] = p1.y;
    cin[4] = p2.x; cin[5] = p2.y; cin[6] = p3.x; cin[7] = p3.y;
  }
  const float4* bf = (const float4*)bias;
  float4 ba = bf[c * 2], bb = bf[c * 2 + 1];
  float bs[8] = {ba.x, ba.y, ba.z, ba.w, bb.x, bb.y, bb.z, bb.w};
  float cx[8];
#pragma unroll
  for (int j = 0; j < 8; ++j) cx[j] = cin[j] + acc[j] * sc + bs[j];
  if (mode == 2) {
    uint4 x1 = x1h16[(size_t)n * 16 + c];
    float2 z0 = h2f2(x1.x), z1 = h2f2(x1.y), z2 = h2f2(x1.z), z3 = h2f2(x1.w);
    float x1v[8] = {z0.x, z0.y, z1.x, z1.y, z2.x, z2.y, z3.x, z3.y};
    uint4 x2 = x2h16[(size_t)n * 16 + c];
    float2 y0 = h2f2(x2.x), y1 = h2f2(x2.y), y2 = h2f2(x2.z), y3 = h2f2(x2.w);
    float x2v[8] = {y0.x, y0.y, y1.x, y1.y, y2.x, y2.y, y3.x, y3.y};
    float4 o0, o1;
    o0.x = (x1v[0] + x2v[0] + cin[0] + cx[0]) * 0.25f;
    o0.y = (x1v[1] + x2v[1] + cin[1] + cx[1]) * 0.25f;
    o0.z = (x1v[2] + x2v[2] + cin[2] + cx[2]) * 0.25f;
    o0.w = (x1v[3] + x2v[3] + cin[3] + cx[3]) * 0.25f;
    o1.x = (x1v[4] + x2v[4] + cin[4] + cx[4]) * 0.25f;
    o1.y = (x1v[5] + x2v[5] + cin[5] + cx[5]) * 0.25f;
    o1.z = (x1v[6] + x2v[6] + cin[6] + cx[6]) * 0.25f;
    o1.w = (x1v[7] + x2v[7] + cin[7] + cx[7]) * 0.25f;
    float4* dp = (float4*)(dout + (size_t)n * DIM);
    dp[c * 2] = o0;
    dp[c * 2 + 1] = o1;
  } else {
    uint4 o;
    o.x = packh2(cx[0], cx[1]);
    o.y = packh2(cx[2], cx[3]);
    o.z = packh2(cx[4], cx[5]);
    o.w = packh2(cx[6], cx[7]);
    couth16[(size_t)n * 16 + c] = o;
  }
}

// ---------------------------------------------------------------------------
static inline int cdiv(int a, int b) { return (a + b - 1) / b; }

extern "C" void kernel_launch(void* const* d_in, const int* in_sizes, int n_in,
                              void* d_out, int out_size, void* d_ws, size_t ws_size,
                              hipStream_t stream)
{
  const float* pois = (const float*)d_in[0];
  const float* traj = (const float*)d_in[1];
  const float* hw   = (const float*)d_in[2];
  const int* node_idx = (const int*)d_in[3];
  const int* edge_idx = (const int*)d_in[4];
  const float* W    = (const float*)d_in[5];
  const float* att  = (const float*)d_in[6];
  const float* bias = (const float*)d_in[7];
  float* dout = (float*)d_out;

  const int N   = in_sizes[0] / DIM;
  const int M   = in_sizes[2];
  const int NNZ = in_sizes[3];
  const int NP  = (N + 63) & ~63;   // row-padded for 64-row MFMA tiles

  char* p = (char*)d_ws;
  auto alloc = [&](size_t bytes) -> void* {
    void* r = (void*)p;
    p += (bytes + 255) & ~(size_t)255;
    return r;
  };
  ushort* xt_h    = (ushort*)alloc((size_t)NP * DIM * 2);
  ushort* pois_h  = (ushort*)alloc((size_t)NP * DIM * 2);
  uint*   cura_h  = (uint*)alloc((size_t)NP * 64 * 4);   // cur1 fp16
  uint*   curb_h  = (uint*)alloc((size_t)NP * 64 * 4);   // cur2 fp16
  ushort* W_swz   = (ushort*)alloc(16384 * 2);
  uint*   eo_h  = (uint*)alloc((size_t)M * (DIM / 2) * 4);
  float2* ns2   = (float2*)alloc((size_t)N * 8);
  float*  s_e  = (float*)alloc((size_t)M * 4);
  float2* se_hw = (float2*)alloc((size_t)M * 8);
  float*  s_n  = (float*)alloc((size_t)N * 4);
  float*  Dinv = (float*)alloc((size_t)N * 4);
  int* ecnt   = (int*)alloc((size_t)M * 4);
  int* ncnt   = (int*)alloc((size_t)N * 4);
  int* ecnt_r = (int*)alloc((size_t)EREP * M * 4);   // replicated counters / prefixes
  int* ncnt_r = (int*)alloc((size_t)NREP * N * 4);
  int* eoff = (int*)alloc((size_t)(M + 1) * 4);
  int* noff = (int*)alloc((size_t)(N + 1) * 4);
  int* r_e  = (int*)alloc((size_t)NNZ * 4);
  int* r_n  = (int*)alloc((size_t)NNZ * 4);
  int* nd_e   = (int*)alloc((size_t)NNZ * 4);
  int* eidx_n = (int*)alloc((size_t)NNZ * 4);
  int* part_e = (int*)alloc(65 * 4);
  int* part_n = (int*)alloc(65 * 4);
  (void)ws_size;

  const int nbE = cdiv(M, 4096), nbN = cdiv(N, 4096);

  // ---- incidence structure (layer-invariant) ----
  hipMemsetAsync(ecnt_r, 0, (size_t)EREP * M * 4, stream);
  hipMemsetAsync(ncnt_r, 0, (size_t)NREP * N * 4, stream);
  hist_rank_kernel<<<cdiv(NNZ, 512), 256, 0, stream>>>(node_idx, edge_idx, ncnt_r, ecnt_r, r_n, r_e, NNZ, M, N);
  repsum_kernel<<<cdiv(M, 256), 256, 0, stream>>>(ecnt_r, ecnt, M, EREP);
  repsum_kernel<<<cdiv(N, 256), 256, 0, stream>>>(ncnt_r, ncnt, N, NREP);
  scan_block_kernel<<<nbE, 1024, 0, stream>>>(ecnt, eoff, part_e, M);
  scan_block_kernel<<<nbN, 1024, 0, stream>>>(ncnt, noff, part_n, N);
  scan_partials_kernel<<<1, 64, 0, stream>>>(part_e, nbE);
  scan_partials_kernel<<<1, 64, 0, stream>>>(part_n, nbN);
  add_off_combine_kernel<<<cdiv(M, 256), 256, 0, stream>>>(eoff, part_e, ecnt_r, M, nbE, EREP);
  add_off_combine_kernel<<<cdiv(N, 256), 256, 0, stream>>>(noff, part_n, ncnt_r, N, nbN, NREP);
  scatter_edge_kernel<<<cdiv(NNZ, 1024), 256, 0, stream>>>(node_idx, edge_idx, r_e, ecnt_r, nd_e, NNZ, M);
  scatter_node_kernel<<<cdiv(NNZ, 1024), 256, 0, stream>>>(node_idx, edge_idx, r_n, ncnt_r, eidx_n, NNZ, N);

  // ---- layer-invariant dense prep ----
  wswz_kernel<<<64, 256, 0, stream>>>(W, W_swz);
  se_kernel<<<cdiv(M, 4), 256, 0, stream>>>(traj, W, att, hw, s_e, se_hw, M);
  poish_kernel<<<cdiv(NP * 16, 256), 256, 0, stream>>>(pois, (uint4*)pois_h, N, NP);

  // ---- layers ----
  // L0: gemm(pois_h); msg2 mode0: cin=pois fp32 -> cura_h
  // L1: gemm(cura_h); msg2 mode1: cin=cura_h   -> curb_h
  // L2: gemm(curb_h); msg2 mode2: cin=curb_h, x1=pois_h(fp16), x2=cura_h -> dout
  for (int layer = 0; layer < 3; ++layer) {
    const ushort* gin = (layer == 0) ? pois_h
                       : (layer == 1) ? (const ushort*)cura_h
                                      : (const ushort*)curb_h;
    gemm_mfma_kernel<<<NP / 64, 256, 0, stream>>>(gin, W_swz, att, xt_h, s_n, N);
    softstat_kernel<<<cdiv(N, 256), 256, 0, stream>>>(noff, eidx_n, s_n, se_hw, ns2, Dinv, N);
    msg1_kernel<<<cdiv(M, 4), 256, 0, stream>>>(eoff, nd_e, ns2, s_e,
                                                (const uint4*)xt_h, (uint4*)eo_h, M);
    const uint* cin_h = (layer == 1) ? cura_h : curb_h;   // unused in mode 0
    uint* couth = (layer == 0) ? cura_h : curb_h;
    msg2_kernel<<<cdiv(N, 4), 256, 0, stream>>>(noff, eidx_n, ns2, Dinv, s_e,
                                                (const uint4*)eo_h, bias,
                                                pois, (const uint4*)cin_h,
                                                (const uint4*)pois_h,
                                                (const uint4*)cura_h,
                                                (uint4*)couth, dout, layer, N);
  }
}

// Round 14
// 679.664 us; speedup vs baseline: 1.1108x; 1.0145x over previous
//
#include <hip/hip_runtime.h>
#include <hip/hip_fp16.h>
#include <cstdint>
#include <cstddef>
#include <cstring>

#define DIM 128
#define NEG_SLOPE 0.2f

#define EREP 16   // replicas for edge counters
#define NREP 8    // replicas for node counters

typedef _Float16 half8v __attribute__((ext_vector_type(8)));
typedef __attribute__((ext_vector_type(4))) float float4v;

// ---- fp16 helpers ----------------------------------------------------------
__device__ __forceinline__ float2 h2f2(uint u) {
  __half2 h;
  __builtin_memcpy(&h, &u, 4);
  return __half22float2(h);
}
__device__ __forceinline__ uint packh2(float lo, float hi) {
  __half2 h = __floats2half2_rn(lo, hi);
  uint u;
  __builtin_memcpy(&u, &h, 4);
  return u;
}
__device__ __forceinline__ ushort f2h_us(float f) {
  __half h = __float2half_rn(f);
  ushort us;
  __builtin_memcpy(&us, &h, 2);
  return us;
}
__device__ __forceinline__ float lrelu(float x) {
  return x >= 0.0f ? x : NEG_SLOPE * x;
}

// ---------------------------------------------------------------------------
// W pre-swizzle into MFMA B-fragment order, fp16 (once):
// ---------------------------------------------------------------------------
__global__ void wswz_kernel(const float* __restrict__ W, ushort* __restrict__ Wswz)
{
  int i = blockIdx.x * 256 + threadIdx.x;   // 0..16383
  int j = i & 7, lane = (i >> 3) & 63, nt = (i >> 9) & 7, kt = i >> 12;
  int k = kt * 32 + (lane >> 4) * 8 + j;
  int col = nt * 16 + (lane & 15);
  Wswz[i] = f2h_us(W[k * 128 + col]);
}

// ---------------------------------------------------------------------------
// pois -> fp16 (padded rows zeroed)
// ---------------------------------------------------------------------------
__global__ void poish_kernel(const float* __restrict__ pois,
                             uint4* __restrict__ pois_h, int N_, int NP)
{
  int i = blockIdx.x * 256 + threadIdx.x;   // each = 8 fp16 = one uint4
  if (i >= NP * 16) return;
  int row = i >> 4;
  uint4 o;
  if (row < N_) {
    const float* src = pois + (size_t)i * 8;
    float4 f0 = *(const float4*)src;
    float4 f1 = *(const float4*)(src + 4);
    o.x = packh2(f0.x, f0.y); o.y = packh2(f0.z, f0.w);
    o.z = packh2(f1.x, f1.y); o.w = packh2(f1.z, f1.w);
  } else { o.x = o.y = o.z = o.w = 0; }
  pois_h[i] = o;
}

// ---------------------------------------------------------------------------
// PREP FUSED: blockIdx-partitioned roles so the latency-parked hist waves
// (fabric atomic cap, VALU idle) OVERLAP with gemm L0 + se compute blocks.
//  blocks [0, histBlocks)                      : hist (2 pairs/thread, grid-stride)
//  blocks [histBlocks, histBlocks+gemmBlocks)  : gemm L0 (Xb = pois_h)
//  blocks [.., +seBlocks)                      : se_kernel
// Replica for pair t stays t&(REP-1)  -> scatter mapping unchanged.
// ---------------------------------------------------------------------------
__global__ __launch_bounds__(256) void prep_fused_kernel(
    // hist
    const int* __restrict__ node_idx, const int* __restrict__ edge_idx,
    int* __restrict__ ncnt_r, int* __restrict__ ecnt_r,
    int* __restrict__ r_n, int* __restrict__ r_e,
    int nnz, int M_, int N_, int histBlocks,
    // gemm L0
    const ushort* __restrict__ Xb, const ushort* __restrict__ Wswz,
    const float* __restrict__ att, ushort* __restrict__ Yb,
    float* __restrict__ s_n, int rowsN, int gemmBlocks,
    // se
    const float* __restrict__ traj, const float* __restrict__ W,
    const float* __restrict__ hw,
    float* __restrict__ s_e, float2* __restrict__ se_hw)
{
  __shared__ ushort st[64 * 128];
  int b = blockIdx.x;
  int tid = threadIdx.x;

  if (b < histBlocks) {
    // ---- hist branch: grid-stride over item PAIRS ----
    int T = b * 256 + tid;
    int stride = histBlocks * 256;
    int npairs = (nnz + 1) >> 1;
    for (int t = T; t < npairs; t += stride) {
      int j = t * 2;
      int* ec = ecnt_r + (size_t)(t & (EREP - 1)) * M_;
      int* nc = ncnt_r + (size_t)(t & (NREP - 1)) * N_;
      if (j + 2 <= nnz) {
        int2 e = *(const int2*)&edge_idx[j];
        int2 n = *(const int2*)&node_idx[j];
        int a0 = atomicAdd(&ec[e.x], 1);
        int a1 = atomicAdd(&ec[e.y], 1);
        int b0 = atomicAdd(&nc[n.x], 1);
        int b1 = atomicAdd(&nc[n.y], 1);
        *(int2*)&r_e[j] = make_int2(a0, a1);
        *(int2*)&r_n[j] = make_int2(b0, b1);
      } else {
        r_e[j] = atomicAdd(&ec[edge_idx[j]], 1);
        r_n[j] = atomicAdd(&nc[node_idx[j]], 1);
      }
    }
    return;
  }

  if (b < histBlocks + gemmBlocks) {
    // ---- gemm L0 branch ----
    int bb = b - histBlocks;
    int w = tid >> 6, lane = tid & 63;
    int q = lane >> 4, c = lane & 15;
    int r0b = bb * 64;
    int r0 = r0b + w * 16;
    float4v acc[8];
#pragma unroll
    for (int nt = 0; nt < 8; ++nt) acc[nt] = (float4v){0.f, 0.f, 0.f, 0.f};
    const ushort* arow = Xb + (size_t)(r0 + c) * DIM + q * 8;
#pragma unroll
    for (int kt = 0; kt < 4; ++kt) {
      half8v a = *(const half8v*)(arow + kt * 32);
#pragma unroll
      for (int nt = 0; nt < 8; ++nt) {
        half8v bfr = *(const half8v*)(Wswz + ((((kt << 3) + nt) << 9) + (lane << 3)));
        acc[nt] = __builtin_amdgcn_mfma_f32_16x16x32_f16(a, bfr, acc[nt], 0, 0, 0);
      }
    }
    float av[8];
#pragma unroll
    for (int nt = 0; nt < 8; ++nt) av[nt] = att[nt * 16 + c];
    float p0 = 0, p1 = 0, p2 = 0, p3 = 0;
#pragma unroll
    for (int nt = 0; nt < 8; ++nt) {
      p0 = fmaf(acc[nt][0], av[nt], p0);
      p1 = fmaf(acc[nt][1], av[nt], p1);
      p2 = fmaf(acc[nt][2], av[nt], p2);
      p3 = fmaf(acc[nt][3], av[nt], p3);
    }
#pragma unroll
    for (int m = 8; m >= 1; m >>= 1) {
      p0 += __shfl_xor(p0, m, 64);
      p1 += __shfl_xor(p1, m, 64);
      p2 += __shfl_xor(p2, m, 64);
      p3 += __shfl_xor(p3, m, 64);
    }
    if (c == 0) {
      int rb = r0 + q * 4;
      if (rb + 0 < rowsN) s_n[rb + 0] = p0;
      if (rb + 1 < rowsN) s_n[rb + 1] = p1;
      if (rb + 2 < rowsN) s_n[rb + 2] = p2;
      if (rb + 3 < rowsN) s_n[rb + 3] = p3;
    }
    ushort* sw = st + w * 2048;
#pragma unroll
    for (int nt = 0; nt < 8; ++nt) {
      sw[(q * 4 + 0) * 128 + nt * 16 + c] = f2h_us(acc[nt][0]);
      sw[(q * 4 + 1) * 128 + nt * 16 + c] = f2h_us(acc[nt][1]);
      sw[(q * 4 + 2) * 128 + nt * 16 + c] = f2h_us(acc[nt][2]);
      sw[(q * 4 + 3) * 128 + nt * 16 + c] = f2h_us(acc[nt][3]);
    }
    __syncthreads();
#pragma unroll
    for (int it = 0; it < 4; ++it) {
      int idx = tid + it * 256;
      int row = idx >> 4, seg = idx & 15;
      *(uint4*)(Yb + (size_t)(r0b + row) * DIM + seg * 8) =
          *(const uint4*)&st[row * 128 + seg * 8];
    }
    return;
  }

  // ---- se branch ----
  {
    float* wv = (float*)st;
    if (tid < 128) {
      const float* wr = W + (size_t)tid * 128;
      float acc = 0.0f;
#pragma unroll 4
      for (int k = 0; k < 128; ++k) acc = fmaf(wr[k], att[DIM + k], acc);
      wv[tid] = acc;
    }
    __syncthreads();
    int e = (b - histBlocks - gemmBlocks) * 4 + (tid >> 6);
    int lane = tid & 63;
    if (e >= M_) return;
    const float* row = traj + (size_t)e * DIM;
    float v = row[lane] * wv[lane] + row[lane + 64] * wv[lane + 64];
#pragma unroll
    for (int d = 32; d > 0; d >>= 1) v += __shfl_down(v, d, 64);
    if (lane == 0) {
      s_e[e] = v;
      float2 g; g.x = v; g.y = hw[e];
      se_hw[e] = g;
    }
  }
}

// ---------------------------------------------------------------------------
// MFMA GEMM (fp16), standalone for layers 1,2.
// ---------------------------------------------------------------------------
__global__ __launch_bounds__(256) void gemm_mfma_kernel(
    const ushort* __restrict__ Xb, const ushort* __restrict__ Wswz,
    const float* __restrict__ att, ushort* __restrict__ Yb,
    float* __restrict__ s_n, int rowsN)
{
  __shared__ ushort st[64 * 128];
  int tid = threadIdx.x;
  int w = tid >> 6, lane = tid & 63;
  int q = lane >> 4, c = lane & 15;
  int r0b = blockIdx.x * 64;
  int r0 = r0b + w * 16;
  float4v acc[8];
#pragma unroll
  for (int nt = 0; nt < 8; ++nt) acc[nt] = (float4v){0.f, 0.f, 0.f, 0.f};
  const ushort* arow = Xb + (size_t)(r0 + c) * DIM + q * 8;
#pragma unroll
  for (int kt = 0; kt < 4; ++kt) {
    half8v a = *(const half8v*)(arow + kt * 32);
#pragma unroll
    for (int nt = 0; nt < 8; ++nt) {
      half8v b = *(const half8v*)(Wswz + ((((kt << 3) + nt) << 9) + (lane << 3)));
      acc[nt] = __builtin_amdgcn_mfma_f32_16x16x32_f16(a, b, acc[nt], 0, 0, 0);
    }
  }
  float av[8];
#pragma unroll
  for (int nt = 0; nt < 8; ++nt) av[nt] = att[nt * 16 + c];
  float p0 = 0, p1 = 0, p2 = 0, p3 = 0;
#pragma unroll
  for (int nt = 0; nt < 8; ++nt) {
    p0 = fmaf(acc[nt][0], av[nt], p0);
    p1 = fmaf(acc[nt][1], av[nt], p1);
    p2 = fmaf(acc[nt][2], av[nt], p2);
    p3 = fmaf(acc[nt][3], av[nt], p3);
  }
#pragma unroll
  for (int m = 8; m >= 1; m >>= 1) {
    p0 += __shfl_xor(p0, m, 64);
    p1 += __shfl_xor(p1, m, 64);
    p2 += __shfl_xor(p2, m, 64);
    p3 += __shfl_xor(p3, m, 64);
  }
  if (c == 0) {
    int rb = r0 + q * 4;
    if (rb + 0 < rowsN) s_n[rb + 0] = p0;
    if (rb + 1 < rowsN) s_n[rb + 1] = p1;
    if (rb + 2 < rowsN) s_n[rb + 2] = p2;
    if (rb + 3 < rowsN) s_n[rb + 3] = p3;
  }
  ushort* sw = st + w * 2048;
#pragma unroll
  for (int nt = 0; nt < 8; ++nt) {
    sw[(q * 4 + 0) * 128 + nt * 16 + c] = f2h_us(acc[nt][0]);
    sw[(q * 4 + 1) * 128 + nt * 16 + c] = f2h_us(acc[nt][1]);
    sw[(q * 4 + 2) * 128 + nt * 16 + c] = f2h_us(acc[nt][2]);
    sw[(q * 4 + 3) * 128 + nt * 16 + c] = f2h_us(acc[nt][3]);
  }
  __syncthreads();
#pragma unroll
  for (int it = 0; it < 4; ++it) {
    int idx = tid + it * 256;
    int row = idx >> 4, seg = idx & 15;
    *(uint4*)(Yb + (size_t)(r0b + row) * DIM + seg * 8) =
        *(const uint4*)&st[row * 128 + seg * 8];
  }
}

// ---------------------------------------------------------------------------
// Per-bin exclusive prefix across replicas (in place) + total into cnt.
// ---------------------------------------------------------------------------
__global__ void repsum_kernel(int* __restrict__ cnt_r, int* __restrict__ cnt,
                              int nbins, int reps)
{
  int b = blockIdx.x * blockDim.x + threadIdx.x;
  if (b >= nbins) return;
  int s = 0;
  for (int r = 0; r < reps; ++r) {
    size_t o = (size_t)r * nbins + b;
    int v = cnt_r[o];
    cnt_r[o] = s;
    s += v;
  }
  cnt[b] = s;
}

// ---------------------------------------------------------------------------
// Two-level exclusive scan
// ---------------------------------------------------------------------------
__global__ __launch_bounds__(1024) void scan_block_kernel(
    const int* __restrict__ cnt, int* __restrict__ off,
    int* __restrict__ partials, int nbins)
{
  __shared__ int ws[16];
  int tid = threadIdx.x, lane = tid & 63, wid = tid >> 6;
  int base = blockIdx.x * 4096 + tid * 4;
  int x0 = base + 0 < nbins ? cnt[base + 0] : 0;
  int x1 = base + 1 < nbins ? cnt[base + 1] : 0;
  int x2 = base + 2 < nbins ? cnt[base + 2] : 0;
  int x3 = base + 3 < nbins ? cnt[base + 3] : 0;
  int t = x0 + x1 + x2 + x3;
  int v = t;
#pragma unroll
  for (int d = 1; d < 64; d <<= 1) {
    int y = __shfl_up(v, d, 64);
    if (lane >= d) v += y;
  }
  if (lane == 63) ws[wid] = v;
  __syncthreads();
  if (tid < 16) {
    int s = ws[tid];
#pragma unroll
    for (int d = 1; d < 16; d <<= 1) {
      int y = __shfl_up(s, d, 16);
      if (tid >= d) s += y;
    }
    ws[tid] = s;
  }
  __syncthreads();
  int pre = (wid > 0 ? ws[wid - 1] : 0) + (v - t);
  if (base + 0 < nbins) off[base + 0] = pre;
  if (base + 1 < nbins) off[base + 1] = pre + x0;
  if (base + 2 < nbins) off[base + 2] = pre + x0 + x1;
  if (base + 3 < nbins) off[base + 3] = pre + x0 + x1 + x2;
  if (tid == 0) partials[blockIdx.x] = ws[15];
}

__global__ __launch_bounds__(64) void scan_partials_kernel(
    int* __restrict__ partials, int nb)
{
  int lane = threadIdx.x;
  int t = lane < nb ? partials[lane] : 0;
  int v = t;
#pragma unroll
  for (int d = 1; d < 64; d <<= 1) {
    int y = __shfl_up(v, d, 64);
    if (lane >= d) v += y;
  }
  if (lane < nb) partials[lane] = v - t;
  if (lane == 63) partials[nb] = v;
}

// add block partials into off AND fold the final offsets into the replica
// prefixes so scatter needs only ONE gather: pos = pre[rep][bin] + local_rank.
__global__ void add_off_combine_kernel(int* __restrict__ off,
                                       const int* __restrict__ partials,
                                       int* __restrict__ pre,
                                       int nbins, int nb, int reps)
{
  int i = blockIdx.x * blockDim.x + threadIdx.x;
  if (i < nbins) {
    int o = off[i] + partials[i >> 12];
    off[i] = o;
    for (int r = 0; r < reps; ++r) pre[(size_t)r * nbins + i] += o;
  }
  if (i == 0) off[nbins] = partials[nb];
}

// ---------------------------------------------------------------------------
// SPLIT atomic-free CSR scatters (replica-aware combined offsets)
// ---------------------------------------------------------------------------
__global__ void scatter_edge_kernel(const int* __restrict__ node_idx,
                                    const int* __restrict__ edge_idx,
                                    const int* __restrict__ r_e,
                                    const int* __restrict__ pre_e,
                                    int* __restrict__ nd_e, int nnz, int M_)
{
  int j = (blockIdx.x * blockDim.x + threadIdx.x) * 4;
  if (j >= nnz) return;
  if (j + 4 <= nnz) {
    const int* p0 = pre_e + (size_t)((j >> 1) & (EREP - 1)) * M_;
    const int* p1 = pre_e + (size_t)(((j >> 1) + 1) & (EREP - 1)) * M_;
    int4 e = *(const int4*)&edge_idx[j];
    int4 n = *(const int4*)&node_idx[j];
    int4 re = *(const int4*)&r_e[j];
    nd_e[p0[e.x] + re.x] = n.x;
    nd_e[p0[e.y] + re.y] = n.y;
    nd_e[p1[e.z] + re.z] = n.z;
    nd_e[p1[e.w] + re.w] = n.w;
  } else {
    for (int k = j; k < nnz; ++k) {
      const int* pp = pre_e + (size_t)((k >> 1) & (EREP - 1)) * M_;
      nd_e[pp[edge_idx[k]] + r_e[k]] = node_idx[k];
    }
  }
}

__global__ void scatter_node_kernel(const int* __restrict__ node_idx,
                                    const int* __restrict__ edge_idx,
                                    const int* __restrict__ r_n,
                                    const int* __restrict__ pre_n,
                                    int* __restrict__ eidx_n, int nnz, int N_)
{
  int j = (blockIdx.x * blockDim.x + threadIdx.x) * 4;
  if (j >= nnz) return;
  if (j + 4 <= nnz) {
    const int* p0 = pre_n + (size_t)((j >> 1) & (NREP - 1)) * N_;
    const int* p1 = pre_n + (size_t)(((j >> 1) + 1) & (NREP - 1)) * N_;
    int4 e = *(const int4*)&edge_idx[j];
    int4 n = *(const int4*)&node_idx[j];
    int4 rn = *(const int4*)&r_n[j];
    eidx_n[p0[n.x] + rn.x] = e.x;
    eidx_n[p0[n.y] + rn.y] = e.y;
    eidx_n[p1[n.z] + rn.z] = e.z;
    eidx_n[p1[n.w] + rn.w] = e.w;
  } else {
    for (int k = j; k < nnz; ++k) {
      const int* pp = pre_n + (size_t)((k >> 1) & (NREP - 1)) * N_;
      eidx_n[pp[node_idx[k]] + r_n[k]] = edge_idx[k];
    }
  }
}

// ---------------------------------------------------------------------------
// Per-node softmax stats + weighted degree
// ---------------------------------------------------------------------------
__global__ void softstat_kernel(const int* __restrict__ noff,
                                const int* __restrict__ eidx_n,
                                const float* __restrict__ s_n,
                                const float2* __restrict__ se_hw,
                                float2* __restrict__ ns2,
                                float* __restrict__ Dinv, int N_)
{
  int n = blockIdx.x * blockDim.x + threadIdx.x;
  if (n >= N_) return;
  int s = noff[n], e1 = noff[n + 1];
  float sn = s_n[n];
  float m = -INFINITY, den = 0.0f, d = 0.0f;
  int t = s;
  for (; t + 4 <= e1; t += 4) {
    int i0 = eidx_n[t], i1 = eidx_n[t + 1], i2 = eidx_n[t + 2], i3 = eidx_n[t + 3];
    float2 g0 = se_hw[i0], g1 = se_hw[i1], g2 = se_hw[i2], g3 = se_hw[i3];
    float l0 = lrelu(sn + g0.x), l1 = lrelu(sn + g1.x);
    float l2 = lrelu(sn + g2.x), l3 = lrelu(sn + g3.x);
    float mm = fmaxf(fmaxf(fmaxf(l0, l1), fmaxf(l2, l3)), m);
    den = den * __expf(m - mm) + __expf(l0 - mm) + __expf(l1 - mm)
        + __expf(l2 - mm) + __expf(l3 - mm);
    m = mm;
    d += g0.y + g1.y + g2.y + g3.y;
  }
  for (; t < e1; ++t) {
    float2 g = se_hw[eidx_n[t]];
    float l = lrelu(sn + g.x);
    float mm = fmaxf(l, m);
    den = den * __expf(m - mm) + __expf(l - mm);
    m = mm;
    d += g.y;
  }
  if (s == e1) m = 0.0f;
  float2 r;
  r.x = sn;
  r.y = m + __logf(den + 1e-16f);
  ns2[n] = r;
  Dinv[n] = d > 0.0f ? 1.0f / d : 0.0f;
}

// ---------------------------------------------------------------------------
// msg1 WIDE: wave per edge; lane = (row-group r = lane>>4, col-group c = lane&15).
// One uint4 gather instruction covers 4 incidence rows (64 lanes x 16B = 1KB).
// ---------------------------------------------------------------------------
__global__ __launch_bounds__(256) void msg1_kernel(
    const int* __restrict__ eoff, const int* __restrict__ nd_e,
    const float2* __restrict__ ns2, const float* __restrict__ s_e,
    const uint4* __restrict__ xt16, uint4* __restrict__ eo16, int M_)
{
  int e = blockIdx.x * 4 + (threadIdx.x >> 6);
  int lane = threadIdx.x & 63;
  int r = lane >> 4, c = lane & 15;
  if (e >= M_) return;
  int s = eoff[e], t1 = eoff[e + 1];
  int len = t1 - s;
  float binv = len > 0 ? 1.0f / (float)len : 0.0f;
  float se = s_e[e];
  float acc[8];
#pragma unroll
  for (int j = 0; j < 8; ++j) acc[j] = 0.0f;
  for (int t = s; t < t1; t += 8) {
#pragma unroll
    for (int h = 0; h < 2; ++h) {
      int tb = t + h * 4;
      if (tb < t1) {
        int ti = tb + r;
        int tc = ti < t1 ? ti : t1 - 1;
        float valid = ti < t1 ? 1.0f : 0.0f;
        int nd = nd_e[tc];
        float2 q = ns2[nd];
        float coef = valid * __expf(lrelu(q.x + se) - q.y);
        uint4 g = xt16[(size_t)nd * 16 + c];
        float2 f0 = h2f2(g.x), f1 = h2f2(g.y), f2 = h2f2(g.z), f3 = h2f2(g.w);
        acc[0] = fmaf(coef, f0.x, acc[0]);
        acc[1] = fmaf(coef, f0.y, acc[1]);
        acc[2] = fmaf(coef, f1.x, acc[2]);
        acc[3] = fmaf(coef, f1.y, acc[3]);
        acc[4] = fmaf(coef, f2.x, acc[4]);
        acc[5] = fmaf(coef, f2.y, acc[5]);
        acc[6] = fmaf(coef, f3.x, acc[6]);
        acc[7] = fmaf(coef, f3.y, acc[7]);
      }
    }
  }
#pragma unroll
  for (int j = 0; j < 8; ++j) {
    acc[j] += __shfl_xor(acc[j], 16, 64);
    acc[j] += __shfl_xor(acc[j], 32, 64);
  }
  if (r == 0) {
    uint4 o;
    o.x = packh2(acc[0] * binv, acc[1] * binv);
    o.y = packh2(acc[2] * binv, acc[3] * binv);
    o.z = packh2(acc[4] * binv, acc[5] * binv);
    o.w = packh2(acc[6] * binv, acc[7] * binv);
    eo16[(size_t)e * 16 + c] = o;
  }
}

// ---------------------------------------------------------------------------
// msg2 WIDE: fp16 residual chain (cin always fp16) + lazy stack-sum epilogue.
//  mode 0/1: out = cur_h (fp16)
//  mode 2:   dout = 0.25*(h(x1h) + h(x2h) + cin + cx)
// ---------------------------------------------------------------------------
__global__ __launch_bounds__(256) void msg2_kernel(
    const int* __restrict__ noff, const int* __restrict__ eidx_n,
    const float2* __restrict__ ns2, const float* __restrict__ Dinv,
    const float* __restrict__ s_e, const uint4* __restrict__ eo16,
    const float* __restrict__ bias,
    const uint4* __restrict__ cin_h16,
    const uint4* __restrict__ x1h16, const uint4* __restrict__ x2h16,
    uint4* __restrict__ couth16, float* __restrict__ dout,
    int mode, int N_)
{
  int n = blockIdx.x * 4 + (threadIdx.x >> 6);
  int lane = threadIdx.x & 63;
  int r = lane >> 4, c = lane & 15;
  if (n >= N_) return;
  int s = noff[n], t1 = noff[n + 1];
  float2 nsv = ns2[n];
  float sn = nsv.x, lz = nsv.y;
  float acc[8];
#pragma unroll
  for (int j = 0; j < 8; ++j) acc[j] = 0.0f;
  for (int t = s; t < t1; t += 8) {
#pragma unroll
    for (int h = 0; h < 2; ++h) {
      int tb = t + h * 4;
      if (tb < t1) {
        int ti = tb + r;
        int tc = ti < t1 ? ti : t1 - 1;
        float valid = ti < t1 ? 1.0f : 0.0f;
        int ed = eidx_n[tc];
        float xs = s_e[ed];
        float coef = valid * __expf(lrelu(sn + xs) - lz);
        uint4 g = eo16[(size_t)ed * 16 + c];
        float2 f0 = h2f2(g.x), f1 = h2f2(g.y), f2 = h2f2(g.z), f3 = h2f2(g.w);
        acc[0] = fmaf(coef, f0.x, acc[0]);
        acc[1] = fmaf(coef, f0.y, acc[1]);
        acc[2] = fmaf(coef, f1.x, acc[2]);
        acc[3] = fmaf(coef, f1.y, acc[3]);
        acc[4] = fmaf(coef, f2.x, acc[4]);
        acc[5] = fmaf(coef, f2.y, acc[5]);
        acc[6] = fmaf(coef, f3.x, acc[6]);
        acc[7] = fmaf(coef, f3.y, acc[7]);
      }
    }
  }
#pragma unroll
  for (int j = 0; j < 8; ++j) {
    acc[j] += __shfl_xor(acc[j], 16, 64);
    acc[j] += __shfl_xor(acc[j], 32, 64);
  }
  if (r != 0) return;
  float sc = Dinv[n];
  uint4 ch = cin_h16[(size_t)n * 16 + c];
  float2 p0 = h2f2(ch.x), p1 = h2f2(ch.y), p2 = h2f2(ch.z), p3 = h2f2(ch.w);
  float cin[8] = {p0.x, p0.y, p1.x, p1.y, p2.x, p2.y, p3.x, p3.y};
  const float4* bf = (const float4*)bias;
  float4 ba = bf[c * 2], bb = bf[c * 2 + 1];
  float bs[8] = {ba.x, ba.y, ba.z, ba.w, bb.x, bb.y, bb.z, bb.w};
  float cx[8];
#pragma unroll
  for (int j = 0; j < 8; ++j) cx[j] = cin[j] + acc[j] * sc + bs[j];
  if (mode == 2) {
    uint4 x1 = x1h16[(size_t)n * 16 + c];
    float2 z0 = h2f2(x1.x), z1 = h2f2(x1.y), z2 = h2f2(x1.z), z3 = h2f2(x1.w);
    float x1v[8] = {z0.x, z0.y, z1.x, z1.y, z2.x, z2.y, z3.x, z3.y};
    uint4 x2 = x2h16[(size_t)n * 16 + c];
    float2 y0 = h2f2(x2.x), y1 = h2f2(x2.y), y2 = h2f2(x2.z), y3 = h2f2(x2.w);
    float x2v[8] = {y0.x, y0.y, y1.x, y1.y, y2.x, y2.y, y3.x, y3.y};
    float4 o0, o1;
    o0.x = (x1v[0] + x2v[0] + cin[0] + cx[0]) * 0.25f;
    o0.y = (x1v[1] + x2v[1] + cin[1] + cx[1]) * 0.25f;
    o0.z = (x1v[2] + x2v[2] + cin[2] + cx[2]) * 0.25f;
    o0.w = (x1v[3] + x2v[3] + cin[3] + cx[3]) * 0.25f;
    o1.x = (x1v[4] + x2v[4] + cin[4] + cx[4]) * 0.25f;
    o1.y = (x1v[5] + x2v[5] + cin[5] + cx[5]) * 0.25f;
    o1.z = (x1v[6] + x2v[6] + cin[6] + cx[6]) * 0.25f;
    o1.w = (x1v[7] + x2v[7] + cin[7] + cx[7]) * 0.25f;
    float4* dp = (float4*)(dout + (size_t)n * DIM);
    dp[c * 2] = o0;
    dp[c * 2 + 1] = o1;
  } else {
    uint4 o;
    o.x = packh2(cx[0], cx[1]);
    o.y = packh2(cx[2], cx[3]);
    o.z = packh2(cx[4], cx[5]);
    o.w = packh2(cx[6], cx[7]);
    couth16[(size_t)n * 16 + c] = o;
  }
}

// ---------------------------------------------------------------------------
static inline int cdiv(int a, int b) { return (a + b - 1) / b; }

extern "C" void kernel_launch(void* const* d_in, const int* in_sizes, int n_in,
                              void* d_out, int out_size, void* d_ws, size_t ws_size,
                              hipStream_t stream)
{
  const float* pois = (const float*)d_in[0];
  const float* traj = (const float*)d_in[1];
  const float* hw   = (const float*)d_in[2];
  const int* node_idx = (const int*)d_in[3];
  const int* edge_idx = (const int*)d_in[4];
  const float* W    = (const float*)d_in[5];
  const float* att  = (const float*)d_in[6];
  const float* bias = (const float*)d_in[7];
  float* dout = (float*)d_out;

  const int N   = in_sizes[0] / DIM;
  const int M   = in_sizes[2];
  const int NNZ = in_sizes[3];
  const int NP  = (N + 63) & ~63;   // row-padded for 64-row MFMA tiles

  char* p = (char*)d_ws;
  auto alloc = [&](size_t bytes) -> void* {
    void* r = (void*)p;
    p += (bytes + 255) & ~(size_t)255;
    return r;
  };
  ushort* xt_h    = (ushort*)alloc((size_t)NP * DIM * 2);
  ushort* pois_h  = (ushort*)alloc((size_t)NP * DIM * 2);
  uint*   cura_h  = (uint*)alloc((size_t)NP * 64 * 4);   // cur1 fp16
  uint*   curb_h  = (uint*)alloc((size_t)NP * 64 * 4);   // cur2 fp16
  ushort* W_swz   = (ushort*)alloc(16384 * 2);
  uint*   eo_h  = (uint*)alloc((size_t)M * (DIM / 2) * 4);
  float2* ns2   = (float2*)alloc((size_t)N * 8);
  float*  s_e  = (float*)alloc((size_t)M * 4);
  float2* se_hw = (float2*)alloc((size_t)M * 8);
  float*  s_n  = (float*)alloc((size_t)N * 4);
  float*  Dinv = (float*)alloc((size_t)N * 4);
  int* ecnt   = (int*)alloc((size_t)M * 4);
  int* ncnt   = (int*)alloc((size_t)N * 4);
  int* ecnt_r = (int*)alloc((size_t)EREP * M * 4);   // replicated counters / prefixes
  int* ncnt_r = (int*)alloc((size_t)NREP * N * 4);
  int* eoff = (int*)alloc((size_t)(M + 1) * 4);
  int* noff = (int*)alloc((size_t)(N + 1) * 4);
  int* r_e  = (int*)alloc((size_t)NNZ * 4);
  int* r_n  = (int*)alloc((size_t)NNZ * 4);
  int* nd_e   = (int*)alloc((size_t)NNZ * 4);
  int* eidx_n = (int*)alloc((size_t)NNZ * 4);
  int* part_e = (int*)alloc(65 * 4);
  int* part_n = (int*)alloc(65 * 4);
  (void)ws_size;

  const int nbE = cdiv(M, 4096), nbN = cdiv(N, 4096);
  const int npairs = (NNZ + 1) >> 1;
  const int histBlocks = cdiv(npairs, 512);   // 2 pairs/thread
  const int gemmBlocks = NP / 64;
  const int seBlocks = cdiv(M, 4);

  // ---- prep: fp16 mirrors + W swizzle (needed by fused gemm L0) ----
  hipMemsetAsync(ecnt_r, 0, (size_t)EREP * M * 4, stream);
  hipMemsetAsync(ncnt_r, 0, (size_t)NREP * N * 4, stream);
  wswz_kernel<<<64, 256, 0, stream>>>(W, W_swz);
  poish_kernel<<<cdiv(NP * 16, 256), 256, 0, stream>>>(pois, (uint4*)pois_h, N, NP);

  // ---- fused: hist (latency-parked) ∥ gemm L0 ∥ se ----
  prep_fused_kernel<<<histBlocks + gemmBlocks + seBlocks, 256, 0, stream>>>(
      node_idx, edge_idx, ncnt_r, ecnt_r, r_n, r_e, NNZ, M, N, histBlocks,
      pois_h, W_swz, att, xt_h, s_n, N, gemmBlocks,
      traj, W, hw, s_e, se_hw);

  // ---- CSR finalize ----
  repsum_kernel<<<cdiv(M, 256), 256, 0, stream>>>(ecnt_r, ecnt, M, EREP);
  repsum_kernel<<<cdiv(N, 256), 256, 0, stream>>>(ncnt_r, ncnt, N, NREP);
  scan_block_kernel<<<nbE, 1024, 0, stream>>>(ecnt, eoff, part_e, M);
  scan_block_kernel<<<nbN, 1024, 0, stream>>>(ncnt, noff, part_n, N);
  scan_partials_kernel<<<1, 64, 0, stream>>>(part_e, nbE);
  scan_partials_kernel<<<1, 64, 0, stream>>>(part_n, nbN);
  add_off_combine_kernel<<<cdiv(M, 256), 256, 0, stream>>>(eoff, part_e, ecnt_r, M, nbE, EREP);
  add_off_combine_kernel<<<cdiv(N, 256), 256, 0, stream>>>(noff, part_n, ncnt_r, N, nbN, NREP);
  scatter_edge_kernel<<<cdiv(NNZ, 1024), 256, 0, stream>>>(node_idx, edge_idx, r_e, ecnt_r, nd_e, NNZ, M);
  scatter_node_kernel<<<cdiv(NNZ, 1024), 256, 0, stream>>>(node_idx, edge_idx, r_n, ncnt_r, eidx_n, NNZ, N);

  // ---- layers ----
  // L0: (gemm done in fused) msg2: cin=pois_h -> cura_h
  // L1: gemm(cura_h); msg2: cin=cura_h -> curb_h
  // L2: gemm(curb_h); msg2 mode2: cin=curb_h, x1=pois_h, x2=cura_h -> dout
  for (int layer = 0; layer < 3; ++layer) {
    if (layer > 0) {
      const ushort* gin = (layer == 1) ? (const ushort*)cura_h
                                       : (const ushort*)curb_h;
      gemm_mfma_kernel<<<NP / 64, 256, 0, stream>>>(gin, W_swz, att, xt_h, s_n, N);
    }
    softstat_kernel<<<cdiv(N, 256), 256, 0, stream>>>(noff, eidx_n, s_n, se_hw, ns2, Dinv, N);
    msg1_kernel<<<cdiv(M, 4), 256, 0, stream>>>(eoff, nd_e, ns2, s_e,
                                                (const uint4*)xt_h, (uint4*)eo_h, M);
    const uint* cin_h = (layer == 0) ? (const uint*)pois_h
                       : (layer == 1) ? cura_h : curb_h;
    uint* couth = (layer == 0) ? cura_h : curb_h;
    msg2_kernel<<<cdiv(N, 4), 256, 0, stream>>>(noff, eidx_n, ns2, Dinv, s_e,
                                                (const uint4*)eo_h, bias,
                                                (const uint4*)cin_h,
                                                (const uint4*)pois_h,
                                                (const uint4*)cura_h,
                                                (uint4*)couth, dout, layer, N);
  }
}